// Round 9
// baseline (372.491 us; speedup 1.0000x reference)
//
#include <hip/hip_runtime.h>
#include <hip/hip_bf16.h>
#include <math.h>

// Problem constants
#define B_DIM 4
#define T_DIM 1024
#define D_DIM 1024
#define M_DIM 16
#define H_DIM 64
#define NT    4096            // B*T
#define NA    17408           // H*M*(M+1)
#define NCAT  18432           // NA + D (v-GEMM fused)
#define EPSV  1e-5f
#define CL    16              // scan chunk length
#define NC    64              // chunks per chain (T/CL)

typedef __bf16 bf16_t;
typedef __bf16 bf16x4 __attribute__((ext_vector_type(4)));
typedef __bf16 bf16x8 __attribute__((ext_vector_type(8)));
typedef float  f32x4  __attribute__((ext_vector_type(4)));
typedef unsigned short u16;
typedef u16 u16x8 __attribute__((ext_vector_type(8)));

#define PBAR() do { asm volatile("" ::: "memory"); __builtin_amdgcn_s_barrier(); asm volatile("" ::: "memory"); } while (0)
#define LGKM0() do { asm volatile("s_waitcnt lgkmcnt(0)" ::: "memory"); __builtin_amdgcn_sched_barrier(0); } while (0)
#define VM0()   do { asm volatile("s_waitcnt vmcnt(0)" ::: "memory"); __builtin_amdgcn_sched_barrier(0); } while (0)

// ---------------------------------------------------------------------------
// prep kernel: rmsnorm (blocks [0,4096)) + weight cvt (blocks >= 4096)
// ---------------------------------------------------------------------------
__global__ __launch_bounds__(256) void prep_kernel(const float* __restrict__ x,
                                                   const float* __restrict__ nw,
                                                   const float* __restrict__ Wa,
                                                   const float* __restrict__ Wv,
                                                   const float* __restrict__ Wo,
                                                   bf16_t* __restrict__ h,
                                                   bf16_t* __restrict__ wcat,
                                                   bf16_t* __restrict__ wo) {
  int tid = threadIdx.x;
  if (blockIdx.x < NT) {
    int row = blockIdx.x;
    const float4* xr = reinterpret_cast<const float4*>(x + (size_t)row * D_DIM);
    float4 xv = xr[tid];
    float ss = xv.x * xv.x + xv.y * xv.y + xv.z * xv.z + xv.w * xv.w;
#pragma unroll
    for (int m = 1; m < 64; m <<= 1) ss += __shfl_xor(ss, m, 64);
    __shared__ float red[4];
    int lane = tid & 63, wid = tid >> 6;
    if (lane == 0) red[wid] = ss;
    __syncthreads();
    float tot = red[0] + red[1] + red[2] + red[3];
    float scale = rsqrtf(tot * (1.0f / D_DIM) + EPSV);
    float4 wv = reinterpret_cast<const float4*>(nw)[tid];
    bf16x4 o;
    o[0] = (bf16_t)(xv.x * scale * wv.x);
    o[1] = (bf16_t)(xv.y * scale * wv.y);
    o[2] = (bf16_t)(xv.z * scale * wv.z);
    o[3] = (bf16_t)(xv.w * scale * wv.w);
    reinterpret_cast<bf16x4*>(h)[(size_t)row * 256 + tid] = o;
  } else {
    constexpr int NA4 = NA * D_DIM / 4;
    constexpr int NV4 = D_DIM * D_DIM / 4;
    constexpr int total = NA4 + 2 * NV4;
    int nb = gridDim.x - NT;
    int idx = (blockIdx.x - NT) * 256 + tid;
    int stride = nb * 256;
    for (; idx < total; idx += stride) {
      const float* src; bf16_t* dst; int j;
      if (idx < NA4)            { src = Wa; dst = wcat; j = idx; }
      else if (idx < NA4 + NV4) { src = Wv; dst = wcat + (size_t)NA * D_DIM; j = idx - NA4; }
      else                      { src = Wo; dst = wo; j = idx - NA4 - NV4; }
      float4 v = reinterpret_cast<const float4*>(src)[j];
      bf16x4 o;
      o[0] = (bf16_t)v.x; o[1] = (bf16_t)v.y; o[2] = (bf16_t)v.z; o[3] = (bf16_t)v.w;
      reinterpret_cast<bf16x4*>(dst)[j] = o;
    }
  }
}

// ---------------------------------------------------------------------------
// Small NT GEMM: 128x128 tile, BK=32 — final projection with residual add.
// ---------------------------------------------------------------------------
__global__ __launch_bounds__(256) void gemm_out_kernel(const bf16_t* __restrict__ A,
                                                       const bf16_t* __restrict__ Bw,
                                                       float* __restrict__ Cout,
                                                       const float* __restrict__ resid,
                                                       int Ndim, int K) {
  constexpr int BM = 128, BN = 128, BK = 32;
  __shared__ bf16_t As[BM * BK];
  __shared__ bf16_t Bs[BN * BK];

  int tid = threadIdx.x;
  int lane = tid & 63;
  int wid = tid >> 6;
  int wm = wid >> 1, wn = wid & 1;
  int bm = blockIdx.x * BM;
  int bn = blockIdx.y * BN;
  int l15 = lane & 15;
  int l4 = lane >> 4;

  f32x4 acc[4][4];
#pragma unroll
  for (int i = 0; i < 4; i++)
#pragma unroll
    for (int j = 0; j < 4; j++) acc[i][j] = (f32x4){0.f, 0.f, 0.f, 0.f};

  const bf16_t* Ag = A + (size_t)bm * K;
  const bf16_t* Bg = Bw + (size_t)bn * K;
  int srow_lane = lane >> 2;
  int scol = (lane & 3) * 8;

  for (int k0 = 0; k0 < K; k0 += BK) {
#pragma unroll
    for (int i = 0; i < 2; i++) {
      int rbase = wid * 32 + i * 16;
      int r = rbase + srow_lane;
      __builtin_amdgcn_global_load_lds(
          (const __attribute__((address_space(1))) void*)(Ag + (size_t)r * K + k0 + scol),
          (__attribute__((address_space(3))) void*)(As + rbase * BK), 16, 0, 0);
      __builtin_amdgcn_global_load_lds(
          (const __attribute__((address_space(1))) void*)(Bg + (size_t)r * K + k0 + scol),
          (__attribute__((address_space(3))) void*)(Bs + rbase * BK), 16, 0, 0);
    }
    __syncthreads();

    const bf16x8* Asv = reinterpret_cast<const bf16x8*>(As);
    const bf16x8* Bsv = reinterpret_cast<const bf16x8*>(Bs);
    bf16x8 af[4], bfr[4];
#pragma unroll
    for (int mf = 0; mf < 4; mf++)
      af[mf] = Asv[(wm * 64 + mf * 16 + l15) * 4 + l4];
#pragma unroll
    for (int nf = 0; nf < 4; nf++)
      bfr[nf] = Bsv[(wn * 64 + nf * 16 + l15) * 4 + l4];
#pragma unroll
    for (int mf = 0; mf < 4; mf++)
#pragma unroll
      for (int nf = 0; nf < 4; nf++)
        acc[mf][nf] = __builtin_amdgcn_mfma_f32_16x16x32_bf16(af[mf], bfr[nf], acc[mf][nf], 0, 0, 0);
    __syncthreads();
  }

#pragma unroll
  for (int mf = 0; mf < 4; mf++)
#pragma unroll
    for (int nf = 0; nf < 4; nf++)
#pragma unroll
      for (int i = 0; i < 4; i++) {
        int row = bm + wm * 64 + mf * 16 + l4 * 4 + i;
        int col = bn + wn * 64 + nf * 16 + l15;
        size_t idx = (size_t)row * Ndim + col;
        Cout[idx] = acc[mf][nf][i] + resid[idx];
      }
}

// ---------------------------------------------------------------------------
// Big NT GEMM (logits + v fused): unchanged (at the K=1024 structural
// ceiling, ~848 TF — m248v2).
// ---------------------------------------------------------------------------
__global__ __launch_bounds__(512, 2) void gemm256_nt_kernel(const bf16_t* __restrict__ A,
                                                            const bf16_t* __restrict__ Bw,
                                                            bf16_t* __restrict__ Clg,
                                                            float* __restrict__ Cv) {
  constexpr int K = 1024;
  constexpr int G = K / 64;        // 16 K-tiles
  __shared__ bf16_t As[2 * 16384];   // 64 KB
  __shared__ bf16_t Bs[2 * 16384];   // 64 KB

  const int tid = threadIdx.x;
  const int lane = tid & 63;
  const int w = tid >> 6;
  const int wm = w >> 2;
  const int wn = w & 3;
  const int l15 = lane & 15;
  const int l4 = lane >> 4;

  const int bm = blockIdx.x * 256;
  const int bn = blockIdx.y * 256;

  const bf16_t* Ag = A + (size_t)bm * K;
  const bf16_t* Bg = Bw + (size_t)bn * K;

  int growi[2], gcoli[2];
#pragma unroll
  for (int j = 0; j < 2; ++j) {
    int E = j * 4096 + tid * 8;
    int sub = E >> 9, e = E & 511;
    int rin = e >> 5, cs = e & 31;
    int cin = cs ^ ((rin & 8) ? 16 : 0);
    growi[j] = (sub >> 1) * 16 + rin;
    gcoli[j] = (sub & 1) * 32 + cin;
  }

  const int fbase = l15 * 32 + ((l4 * 8) ^ ((l15 & 8) ? 16 : 0));

  f32x4 acc[8][4];
#pragma unroll
  for (int i = 0; i < 8; i++)
#pragma unroll
    for (int j = 0; j < 4; j++) acc[i][j] = (f32x4){0.f, 0.f, 0.f, 0.f};

  bf16x8 ALo[8], AHi[8], B0r[4], B1r[4];

  auto stageHalf = [&](const bf16_t* Gp, bf16_t* Lp, int bufp, int half, int t2) {
#pragma unroll
    for (int j = 0; j < 2; ++j) {
      const bf16_t* src = Gp + (size_t)(half * 128 + growi[j]) * K + t2 * 64 + gcoli[j];
      __builtin_amdgcn_global_load_lds(
          (const __attribute__((address_space(1))) void*)src,
          (__attribute__((address_space(3))) void*)(Lp + bufp * 16384 + half * 8192 + j * 4096 + w * 512),
          16, 0, 0);
    }
  };

  auto rdA4 = [&](bf16x8* dst, int bufp, int rgrpBase) {
    const bf16_t* base = As + bufp * 16384;
#pragma unroll
    for (int mf = 0; mf < 4; ++mf)
#pragma unroll
      for (int kk = 0; kk < 2; ++kk)
        dst[mf * 2 + kk] = *reinterpret_cast<const bf16x8*>(base + ((rgrpBase + mf) * 2 + kk) * 512 + fbase);
  };
  auto rdA2 = [&](bf16x8* dst, int bufp, int rgrpBase) {
    const bf16_t* base = As + bufp * 16384;
#pragma unroll
    for (int mf = 0; mf < 2; ++mf)
#pragma unroll
      for (int kk = 0; kk < 2; ++kk)
        dst[mf * 2 + kk] = *reinterpret_cast<const bf16x8*>(base + ((rgrpBase + mf) * 2 + kk) * 512 + fbase);
  };
  auto rdB = [&](bf16x8* dst, int bufp, int nfBase) {
    const bf16_t* base = Bs + bufp * 16384;
#pragma unroll
    for (int nf = 0; nf < 2; ++nf)
#pragma unroll
      for (int kk = 0; kk < 2; ++kk)
        dst[nf * 2 + kk] = *reinterpret_cast<const bf16x8*>(base + ((wn * 4 + nfBase + nf) * 2 + kk) * 512 + fbase);
  };
  auto MM = [&](const bf16x8* Af, const bf16x8* Bf, int mfB, int nfB) {
    __builtin_amdgcn_s_setprio(1);
#pragma unroll
    for (int mf = 0; mf < 4; ++mf)
#pragma unroll
      for (int nf = 0; nf < 2; ++nf)
#pragma unroll
        for (int kk = 0; kk < 2; ++kk)
          acc[mfB + mf][nfB + nf] = __builtin_amdgcn_mfma_f32_16x16x32_bf16(
              Af[mf * 2 + kk], Bf[nf * 2 + kk], acc[mfB + mf][nfB + nf], 0, 0, 0);
    __builtin_amdgcn_s_setprio(0);
  };

  // -------- prologue --------
  stageHalf(Bg, Bs, 0, 0, 0);
  stageHalf(Bg, Bs, 0, 1, 0);
  stageHalf(Ag, As, 0, 0, 0);
  stageHalf(Ag, As, 0, 1, 0);
  stageHalf(Ag, As, 1, 0, 1);
  stageHalf(Ag, As, 1, 1, 1);
  asm volatile("s_waitcnt vmcnt(0)" ::: "memory");
  PBAR();
  rdA4(ALo, 0, wm * 8);

#pragma unroll 1
  for (int t = 0; t < G; ++t) {
    const int buf = t & 1;
    const int nbuf = buf ^ 1;

    // ---- P1 ----
    rdB(B0r, buf, 0);
    rdA2(AHi, buf, wm * 8 + 4);
    if (t + 1 < G) stageHalf(Bg, Bs, nbuf, 0, t + 1);
    PBAR();
    MM(ALo, B0r, 0, 0);
    PBAR();

    // ---- P2 ----
    rdB(B1r, buf, 2);
    rdA2(AHi + 4, buf, wm * 8 + 6);
    if (t + 1 < G) stageHalf(Bg, Bs, nbuf, 1, t + 1);
    PBAR();
    MM(ALo, B1r, 0, 2);
    if (t + 1 < G) asm volatile("s_waitcnt vmcnt(4)" ::: "memory");
    PBAR();

    // ---- P3 ----
    if (t + 1 < G) rdA4(ALo, nbuf, wm * 8);
    if (t + 2 < G) stageHalf(Ag, As, buf, 0, t + 2);
    PBAR();
    MM(AHi, B0r, 4, 0);
    PBAR();

    // ---- P4 ----
    if (t + 2 < G) stageHalf(Ag, As, buf, 1, t + 2);
    PBAR();
    MM(AHi, B1r, 4, 2);
    if (t + 2 < G)      asm volatile("s_waitcnt vmcnt(4)" ::: "memory");
    else if (t + 1 < G) asm volatile("s_waitcnt vmcnt(0)" ::: "memory");
    PBAR();
  }

  // -------- epilogue --------
  if (blockIdx.y < 68) {
#pragma unroll
    for (int mf = 0; mf < 8; ++mf)
#pragma unroll
      for (int nf = 0; nf < 4; ++nf)
#pragma unroll
        for (int i = 0; i < 4; ++i) {
          int row = bm + wm * 128 + mf * 16 + l4 * 4 + i;
          int col = bn + wn * 64 + nf * 16 + l15;
          Clg[(size_t)row * NA + col] = (bf16_t)acc[mf][nf][i];
        }
  } else {
    int cb = bn - NA;
#pragma unroll
    for (int mf = 0; mf < 8; ++mf)
#pragma unroll
      for (int nf = 0; nf < 4; ++nf)
#pragma unroll
        for (int i = 0; i < 4; ++i) {
          int row = bm + wm * 128 + mf * 16 + l4 * 4 + i;
          int col = cb + wn * 64 + nf * 16 + l15;
          Cv[(size_t)row * D_DIM + col] = acc[mf][nf][i];
        }
  }
}

// ---------------------------------------------------------------------------
// Coalesced group staging: a 16-lane group's 544B logits block (272 bf16)
// loaded as 34 16B chunks: lane i loads chunks {i, 16+i} (+ {32+i} if i<2),
// bounced through LDS, then read back as 17 u16 per lane.
// ---------------------------------------------------------------------------
__device__ __forceinline__ void loadBlk(const bf16_t* __restrict__ lg,
                                        int r, int h, int i,
                                        u16x8& c0, u16x8& c1, u16x8& c2) {
  const u16x8* p = reinterpret_cast<const u16x8*>(lg + (size_t)r * NA + h * 272);
  c0 = p[i];
  c1 = p[16 + i];
  if (i < 2) c2 = p[32 + i];
}

__device__ __forceinline__ void writeBlk(u16* __restrict__ Lbg, int i,
                                         const u16x8& c0, const u16x8& c1, const u16x8& c2) {
  u16x8* q = reinterpret_cast<u16x8*>(Lbg);
  q[i] = c0;
  q[16 + i] = c1;
  if (i < 2) q[32 + i] = c2;
}

__device__ __forceinline__ void softmax17lds(const u16* __restrict__ Lrow, float vval,
                                             f32x4& a0, f32x4& a1, f32x4& a2, f32x4& a3,
                                             float& u) {
  float e[17];
  float mx = -1e30f;
#pragma unroll
  for (int j = 0; j < 17; ++j) {
    e[j] = __uint_as_float(((unsigned)Lrow[j]) << 16);
    mx = fmaxf(mx, e[j]);
  }
  float s = 0.f;
#pragma unroll
  for (int j = 0; j < 17; ++j) {
    e[j] = __expf(e[j] - mx);
    s += e[j];
  }
  float inv = 1.0f / s;
  a0 = (f32x4){e[1] * inv, e[2] * inv, e[3] * inv, e[4] * inv};
  a1 = (f32x4){e[5] * inv, e[6] * inv, e[7] * inv, e[8] * inv};
  a2 = (f32x4){e[9] * inv, e[10] * inv, e[11] * inv, e[12] * inv};
  a3 = (f32x4){e[13] * inv, e[14] * inv, e[15] * inv, e[16] * inv};
  u = e[0] * inv * vval;
}

// ---------------------------------------------------------------------------
// scanA: per (chain, chunk) chunk summary (P, q) — coalesced staged loads
// ---------------------------------------------------------------------------
__global__ __launch_bounds__(256) void scanA_kernel(const bf16_t* __restrict__ lg,
                                                    const float* __restrict__ v,
                                                    float* __restrict__ sum) {
  int bc = blockIdx.x;
  int b = bc >> 6;
  int c = bc & 63;
  int g = threadIdx.x >> 4;
  int i = threadIdx.x & 15;
  int h = blockIdx.y * 16 + g;
  int chain = b * 64 + h;
  int rbase = b * T_DIM + c * CL;

  __shared__ float Arows[16][16][16];   // 16 KB
  __shared__ float Us[16][16];          //  1 KB
  __shared__ u16 Lb[2][16][288];        // 18 KB

  f32x4 R0 = (f32x4){i == 0 ? 1.f : 0.f, i == 1 ? 1.f : 0.f, i == 2 ? 1.f : 0.f, i == 3 ? 1.f : 0.f};
  f32x4 R1 = (f32x4){i == 4 ? 1.f : 0.f, i == 5 ? 1.f : 0.f, i == 6 ? 1.f : 0.f, i == 7 ? 1.f : 0.f};
  f32x4 R2 = (f32x4){i == 8 ? 1.f : 0.f, i == 9 ? 1.f : 0.f, i == 10 ? 1.f : 0.f, i == 11 ? 1.f : 0.f};
  f32x4 R3 = (f32x4){i == 12 ? 1.f : 0.f, i == 13 ? 1.f : 0.f, i == 14 ? 1.f : 0.f, i == 15 ? 1.f : 0.f};
  float q = 0.f;

  // prologue: stage step CL-1 into buf 0
  {
    u16x8 c0, c1, c2;
    loadBlk(lg, rbase + CL - 1, h, i, c0, c1, c2);
    VM0();
    writeBlk(&Lb[0][g][0], i, c0, c1, c2);
  }
  float vv = v[(size_t)(rbase + CL - 1) * D_DIM + h * 16 + i];
  int cur = 0;

#pragma unroll 1
  for (int tau = CL - 1; tau >= 0; --tau) {
    int taun = (tau > 0) ? tau - 1 : 0;
    u16x8 n0, n1, n2;
    loadBlk(lg, rbase + taun, h, i, n0, n1, n2);
    float vn = v[(size_t)(rbase + taun) * D_DIM + h * 16 + i];

    LGKM0();   // prior Lb writes visible
    f32x4 a0, a1, a2, a3;
    float uu;
    softmax17lds(&Lb[cur][g][i * 17], vv, a0, a1, a2, a3, uu);

    *reinterpret_cast<f32x4*>(&Arows[g][i][0]) = a0;
    *reinterpret_cast<f32x4*>(&Arows[g][i][4]) = a1;
    *reinterpret_cast<f32x4*>(&Arows[g][i][8]) = a2;
    *reinterpret_cast<f32x4*>(&Arows[g][i][12]) = a3;
    Us[g][i] = uu;
    LGKM0();

    f32x4 u0 = *reinterpret_cast<const f32x4*>(&Us[g][0]);
    f32x4 u1 = *reinterpret_cast<const f32x4*>(&Us[g][4]);
    f32x4 u2 = *reinterpret_cast<const f32x4*>(&Us[g][8]);
    f32x4 u3 = *reinterpret_cast<const f32x4*>(&Us[g][12]);
    float qa = fmaf(R0[0], u0[0], fmaf(R0[1], u0[1], fmaf(R0[2], u0[2], R0[3] * u0[3])));
    float qb = fmaf(R1[0], u1[0], fmaf(R1[1], u1[1], fmaf(R1[2], u1[2], R1[3] * u1[3])));
    float qc = fmaf(R2[0], u2[0], fmaf(R2[1], u2[1], fmaf(R2[2], u2[2], R2[3] * u2[3])));
    float qd = fmaf(R3[0], u3[0], fmaf(R3[1], u3[1], fmaf(R3[2], u3[2], R3[3] * u3[3])));
    q += (qa + qb) + (qc + qd);

    f32x4 m0 = (f32x4){0.f, 0.f, 0.f, 0.f}, m1 = m0, m2 = m0, m3 = m0;
#pragma unroll
    for (int k = 0; k < 16; ++k) {
      float rk = (k < 4) ? R0[k & 3] : (k < 8) ? R1[k & 3] : (k < 12) ? R2[k & 3] : R3[k & 3];
      f32x4 b0 = *reinterpret_cast<const f32x4*>(&Arows[g][k][0]);
      f32x4 b1 = *reinterpret_cast<const f32x4*>(&Arows[g][k][4]);
      f32x4 b2 = *reinterpret_cast<const f32x4*>(&Arows[g][k][8]);
      f32x4 b3 = *reinterpret_cast<const f32x4*>(&Arows[g][k][12]);
#pragma unroll
      for (int e2 = 0; e2 < 4; ++e2) {
        m0[e2] = fmaf(rk, b0[e2], m0[e2]);
        m1[e2] = fmaf(rk, b1[e2], m1[e2]);
        m2[e2] = fmaf(rk, b2[e2], m2[e2]);
        m3[e2] = fmaf(rk, b3[e2], m3[e2]);
      }
    }
    R0 = m0; R1 = m1; R2 = m2; R3 = m3;

    // stage next step
    VM0();
    writeBlk(&Lb[cur ^ 1][g][0], i, n0, n1, n2);
    vv = vn;
    cur ^= 1;
  }

  float* sp = sum + (size_t)(chain * NC + c) * 272;
  *reinterpret_cast<f32x4*>(&sp[i * 16 + 0]) = R0;
  *reinterpret_cast<f32x4*>(&sp[i * 16 + 4]) = R1;
  *reinterpret_cast<f32x4*>(&sp[i * 16 + 8]) = R2;
  *reinterpret_cast<f32x4*>(&sp[i * 16 + 12]) = R3;
  sp[256 + i] = q;
}

// ---------------------------------------------------------------------------
// scanB: serial scan over 64 chunk summaries per chain (unchanged)
// ---------------------------------------------------------------------------
__global__ __launch_bounds__(64) void scanB_kernel(const float* __restrict__ sum,
                                                   float* __restrict__ sinit) {
  int chain = blockIdx.x;
  int lane = threadIdx.x;
  int i = lane & 15;

  __shared__ float seg[2][2176];

  const float* gbase = sum + (size_t)chain * NC * 272;

  auto load_seg = [&](int s, int buf) {
#pragma unroll
    for (int r = 0; r < 9; ++r) {
      int idx = r * 256 + lane * 4;
      if (idx < 2176) {
        __builtin_amdgcn_global_load_lds(
            (const __attribute__((address_space(1))) void*)(gbase + (size_t)s * 2176 + idx),
            (__attribute__((address_space(3))) void*)(&seg[buf][r * 256]), 16, 0, 0);
      }
    }
  };

  load_seg(0, 0);
  VM0();

  f32x4 S0 = (f32x4){0.f, 0.f, 0.f, 0.f}, S1 = S0, S2 = S0, S3 = S0;
  float own = 0.f;

  for (int sg = 0; sg < 8; ++sg) {
    int buf = sg & 1;
    if (sg + 1 < 8) load_seg(sg + 1, buf ^ 1);
#pragma unroll 1
    for (int cc = 0; cc < 8; ++cc) {
      int c = sg * 8 + cc;
      const float* Pb = &seg[buf][cc * 272];
      if (lane < 16) sinit[(size_t)(chain * NC + c) * 16 + i] = own;

      f32x4 p0 = *reinterpret_cast<const f32x4*>(&Pb[i * 16 + 0]);
      f32x4 p1 = *reinterpret_cast<const f32x4*>(&Pb[i * 16 + 4]);
      f32x4 p2 = *reinterpret_cast<const f32x4*>(&Pb[i * 16 + 8]);
      f32x4 p3 = *reinterpret_cast<const f32x4*>(&Pb[i * 16 + 12]);
      float qq = Pb[256 + i];

      float pa = fmaf(p0[0], S0[0], fmaf(p0[1], S0[1], fmaf(p0[2], S0[2], p0[3] * S0[3])));
      float pb = fmaf(p1[0], S1[0], fmaf(p1[1], S1[1], fmaf(p1[2], S1[2], p1[3] * S1[3])));
      float pc = fmaf(p2[0], S2[0], fmaf(p2[1], S2[1], fmaf(p2[2], S2[2], p2[3] * S2[3])));
      float pd = fmaf(p3[0], S3[0], fmaf(p3[1], S3[1], fmaf(p3[2], S3[2], p3[3] * S3[3])));
      float p = (pa + pb) + (pc + pd) + qq;
      own = p;

#pragma unroll
      for (int j = 0; j < 4; ++j) {
        S0[j] = __shfl(p, j, 64);
        S1[j] = __shfl(p, 4 + j, 64);
        S2[j] = __shfl(p, 8 + j, 64);
        S3[j] = __shfl(p, 12 + j, 64);
      }
    }
    if (sg + 1 < 8) VM0();
  }
}

// ---------------------------------------------------------------------------
// scanC: re-run each chunk from its s_init, writing y — coalesced staged loads
// ---------------------------------------------------------------------------
__global__ __launch_bounds__(256) void scanC_kernel(const bf16_t* __restrict__ lg,
                                                    const float* __restrict__ v,
                                                    const float* __restrict__ sinit,
                                                    bf16_t* __restrict__ y) {
  int bc = blockIdx.x;
  int b = bc >> 6;
  int c = bc & 63;
  int g = threadIdx.x >> 4;
  int i = threadIdx.x & 15;
  int h = blockIdx.y * 16 + g;
  int chain = b * 64 + h;
  int rbase = b * T_DIM + c * CL;

  __shared__ float Sb[16][16];
  __shared__ u16 Lb[2][16][288];

  const float* ip = sinit + (size_t)(chain * NC + c) * 16;
  f32x4 S0 = *reinterpret_cast<const f32x4*>(&ip[0]);
  f32x4 S1 = *reinterpret_cast<const f32x4*>(&ip[4]);
  f32x4 S2 = *reinterpret_cast<const f32x4*>(&ip[8]);
  f32x4 S3 = *reinterpret_cast<const f32x4*>(&ip[12]);

  {
    u16x8 c0, c1, c2;
    loadBlk(lg, rbase, h, i, c0, c1, c2);
    VM0();
    writeBlk(&Lb[0][g][0], i, c0, c1, c2);
  }
  float vv = v[(size_t)rbase * D_DIM + h * 16 + i];
  int cur = 0;

#pragma unroll 1
  for (int t = 0; t < CL; ++t) {
    int tn = (t < CL - 1) ? t + 1 : t;
    u16x8 n0, n1, n2;
    loadBlk(lg, rbase + tn, h, i, n0, n1, n2);
    float vn = v[(size_t)(rbase + tn) * D_DIM + h * 16 + i];

    LGKM0();   // prior Lb writes + Sb visible
    f32x4 a0, a1, a2, a3;
    float uu;
    softmax17lds(&Lb[cur][g][i * 17], vv, a0, a1, a2, a3, uu);

    float pa = fmaf(a0[0], S0[0], fmaf(a0[1], S0[1], fmaf(a0[2], S0[2], a0[3] * S0[3])));
    float pb = fmaf(a1[0], S1[0], fmaf(a1[1], S1[1], fmaf(a1[2], S1[2], a1[3] * S1[3])));
    float pc = fmaf(a2[0], S2[0], fmaf(a2[1], S2[1], fmaf(a2[2], S2[2], a2[3] * S2[3])));
    float pd = fmaf(a3[0], S3[0], fmaf(a3[1], S3[1], fmaf(a3[2], S3[2], a3[3] * S3[3])));
    float p = (pa + pb) + (pc + pd) + uu;

    y[(size_t)(rbase + t) * D_DIM + h * 16 + i] = (bf16_t)p;

    Sb[g][i] = p;
    LGKM0();
    S0 = *reinterpret_cast<const f32x4*>(&Sb[g][0]);
    S1 = *reinterpret_cast<const f32x4*>(&Sb[g][4]);
    S2 = *reinterpret_cast<const f32x4*>(&Sb[g][8]);
    S3 = *reinterpret_cast<const f32x4*>(&Sb[g][12]);

    VM0();
    writeBlk(&Lb[cur ^ 1][g][0], i, n0, n1, n2);
    vv = vn;
    cur ^= 1;
  }
}

// ---------------------------------------------------------------------------
extern "C" void kernel_launch(void* const* d_in, const int* in_sizes, int n_in,
                              void* d_out, int out_size, void* d_ws, size_t ws_size,
                              hipStream_t stream) {
  const float* x      = (const float*)d_in[0];
  const float* norm_w = (const float*)d_in[1];
  const float* W_v    = (const float*)d_in[2];
  const float* W_a    = (const float*)d_in[3];
  const float* W_out  = (const float*)d_in[4];

  char* ws = (char*)d_ws;
  size_t off = 0;
  auto alloc = [&](size_t bytes) {
    void* p = ws + off;
    off += (bytes + 255) & ~(size_t)255;
    return p;
  };
  bf16_t* wcat = (bf16_t*)alloc((size_t)NCAT * D_DIM * 2);         // 37.75 MB
  bf16_t* wo_b = (bf16_t*)alloc((size_t)D_DIM * D_DIM * 2);        // 2 MB
  bf16_t* h_b  = (bf16_t*)alloc((size_t)NT * D_DIM * 2);           // 8 MB
  float*  v_f  = (float*)alloc((size_t)NT * D_DIM * 4);            // 16 MB
  bf16_t* lg_b = (bf16_t*)alloc((size_t)NT * NA * 2);              // 142.6 MB
  bf16_t* y_b  = (bf16_t*)alloc((size_t)NT * D_DIM * 2);           // 8 MB
  float*  sum_f   = (float*)alloc((size_t)256 * NC * 272 * 4);     // 17.8 MB
  float*  sinit_f = (float*)alloc((size_t)256 * NC * 16 * 4);      // 1.05 MB

  prep_kernel<<<NT + 2048, 256, 0, stream>>>(x, norm_w, W_a, W_v, W_out,
                                             h_b, wcat, wo_b);

  gemm256_nt_kernel<<<dim3(NT / 256, NCAT / 256), 512, 0, stream>>>(h_b, wcat, lg_b, v_f);

  scanA_kernel<<<dim3(256, 4), 256, 0, stream>>>(lg_b, v_f, sum_f);
  scanB_kernel<<<256, 64, 0, stream>>>(sum_f, sinit_f);
  scanC_kernel<<<dim3(256, 4), 256, 0, stream>>>(lg_b, v_f, sinit_f, y_b);

  gemm_out_kernel<<<dim3(NT / 128, D_DIM / 128), 256, 0, stream>>>(
      y_b, wo_b, (float*)d_out, x, D_DIM, D_DIM);
}

// Round 10
// 337.292 us; speedup vs baseline: 1.1044x; 1.1044x over previous
//
#include <hip/hip_runtime.h>
#include <hip/hip_bf16.h>
#include <math.h>

// Problem constants
#define B_DIM 4
#define T_DIM 1024
#define D_DIM 1024
#define M_DIM 16
#define H_DIM 64
#define NT    4096            // B*T
#define NA    17408           // H*M*(M+1)
#define NCAT  18432           // NA + D (v-GEMM fused)
#define EPSV  1e-5f
#define CL    16              // scan chunk length
#define NC    64              // chunks per chain (T/CL)

typedef __bf16 bf16_t;
typedef __bf16 bf16x4 __attribute__((ext_vector_type(4)));
typedef __bf16 bf16x8 __attribute__((ext_vector_type(8)));
typedef float  f32x4  __attribute__((ext_vector_type(4)));
typedef unsigned short u16;

#define PBAR() do { asm volatile("" ::: "memory"); __builtin_amdgcn_s_barrier(); asm volatile("" ::: "memory"); } while (0)
#define VM0()   do { asm volatile("s_waitcnt vmcnt(0)" ::: "memory"); __builtin_amdgcn_sched_barrier(0); } while (0)

// ---------------------------------------------------------------------------
// prep kernel: rmsnorm (blocks [0,4096)) + weight cvt (blocks >= 4096).
// W_a rows are PERMUTED so the logits GEMM emits gates in [h][j][i] order:
//   src row n = h*272 + i*17 + j  ->  dst row n' = h*272 + j*16 + i
// This makes scan-side per-lane gate loads coalesced (32B per 16-lane group).
// ---------------------------------------------------------------------------
__global__ __launch_bounds__(256) void prep_kernel(const float* __restrict__ x,
                                                   const float* __restrict__ nw,
                                                   const float* __restrict__ Wa,
                                                   const float* __restrict__ Wv,
                                                   const float* __restrict__ Wo,
                                                   bf16_t* __restrict__ h,
                                                   bf16_t* __restrict__ wcat,
                                                   bf16_t* __restrict__ wo) {
  int tid = threadIdx.x;
  if (blockIdx.x < NT) {
    int row = blockIdx.x;
    const float4* xr = reinterpret_cast<const float4*>(x + (size_t)row * D_DIM);
    float4 xv = xr[tid];
    float ss = xv.x * xv.x + xv.y * xv.y + xv.z * xv.z + xv.w * xv.w;
#pragma unroll
    for (int m = 1; m < 64; m <<= 1) ss += __shfl_xor(ss, m, 64);
    __shared__ float red[4];
    int lane = tid & 63, wid = tid >> 6;
    if (lane == 0) red[wid] = ss;
    __syncthreads();
    float tot = red[0] + red[1] + red[2] + red[3];
    float scale = rsqrtf(tot * (1.0f / D_DIM) + EPSV);
    float4 wv = reinterpret_cast<const float4*>(nw)[tid];
    bf16x4 o;
    o[0] = (bf16_t)(xv.x * scale * wv.x);
    o[1] = (bf16_t)(xv.y * scale * wv.y);
    o[2] = (bf16_t)(xv.z * scale * wv.z);
    o[3] = (bf16_t)(xv.w * scale * wv.w);
    reinterpret_cast<bf16x4*>(h)[(size_t)row * 256 + tid] = o;
  } else {
    constexpr int NA4 = NA * D_DIM / 4;     // f32x4 count of W_a
    constexpr int NV4 = D_DIM * D_DIM / 4;
    constexpr int total = NA4 + 2 * NV4;
    int nb = gridDim.x - NT;
    int idx = (blockIdx.x - NT) * 256 + tid;
    int stride = nb * 256;
    for (; idx < total; idx += stride) {
      const float* src; bf16_t* dst; int js, jd;
      if (idx < NA4) {
        src = Wa; dst = wcat; js = idx;
        int row = idx >> 8;          // source row (256 f32x4 per row)
        int c4 = idx & 255;
        int hh = row / 272, r = row - hh * 272;
        int ii = r / 17, jj = r - ii * 17;
        int nrow = hh * 272 + jj * 16 + ii;   // permuted row
        jd = (nrow << 8) + c4;
      } else if (idx < NA4 + NV4) {
        src = Wv; dst = wcat + (size_t)NA * D_DIM; js = idx - NA4; jd = js;
      } else {
        src = Wo; dst = wo; js = idx - NA4 - NV4; jd = js;
      }
      float4 v = reinterpret_cast<const float4*>(src)[js];
      bf16x4 o;
      o[0] = (bf16_t)v.x; o[1] = (bf16_t)v.y; o[2] = (bf16_t)v.z; o[3] = (bf16_t)v.w;
      reinterpret_cast<bf16x4*>(dst)[jd] = o;
    }
  }
}

// ---------------------------------------------------------------------------
// Small NT GEMM: 128x128 tile, BK=32 — final projection with residual add.
// ---------------------------------------------------------------------------
__global__ __launch_bounds__(256) void gemm_out_kernel(const bf16_t* __restrict__ A,
                                                       const bf16_t* __restrict__ Bw,
                                                       float* __restrict__ Cout,
                                                       const float* __restrict__ resid,
                                                       int Ndim, int K) {
  constexpr int BM = 128, BN = 128, BK = 32;
  __shared__ bf16_t As[BM * BK];
  __shared__ bf16_t Bs[BN * BK];

  int tid = threadIdx.x;
  int lane = tid & 63;
  int wid = tid >> 6;
  int wm = wid >> 1, wn = wid & 1;
  int bm = blockIdx.x * BM;
  int bn = blockIdx.y * BN;
  int l15 = lane & 15;
  int l4 = lane >> 4;

  f32x4 acc[4][4];
#pragma unroll
  for (int i = 0; i < 4; i++)
#pragma unroll
    for (int j = 0; j < 4; j++) acc[i][j] = (f32x4){0.f, 0.f, 0.f, 0.f};

  const bf16_t* Ag = A + (size_t)bm * K;
  const bf16_t* Bg = Bw + (size_t)bn * K;
  int srow_lane = lane >> 2;
  int scol = (lane & 3) * 8;

  for (int k0 = 0; k0 < K; k0 += BK) {
#pragma unroll
    for (int i = 0; i < 2; i++) {
      int rbase = wid * 32 + i * 16;
      int r = rbase + srow_lane;
      __builtin_amdgcn_global_load_lds(
          (const __attribute__((address_space(1))) void*)(Ag + (size_t)r * K + k0 + scol),
          (__attribute__((address_space(3))) void*)(As + rbase * BK), 16, 0, 0);
      __builtin_amdgcn_global_load_lds(
          (const __attribute__((address_space(1))) void*)(Bg + (size_t)r * K + k0 + scol),
          (__attribute__((address_space(3))) void*)(Bs + rbase * BK), 16, 0, 0);
    }
    __syncthreads();

    const bf16x8* Asv = reinterpret_cast<const bf16x8*>(As);
    const bf16x8* Bsv = reinterpret_cast<const bf16x8*>(Bs);
    bf16x8 af[4], bfr[4];
#pragma unroll
    for (int mf = 0; mf < 4; mf++)
      af[mf] = Asv[(wm * 64 + mf * 16 + l15) * 4 + l4];
#pragma unroll
    for (int nf = 0; nf < 4; nf++)
      bfr[nf] = Bsv[(wn * 64 + nf * 16 + l15) * 4 + l4];
#pragma unroll
    for (int mf = 0; mf < 4; mf++)
#pragma unroll
      for (int nf = 0; nf < 4; nf++)
        acc[mf][nf] = __builtin_amdgcn_mfma_f32_16x16x32_bf16(af[mf], bfr[nf], acc[mf][nf], 0, 0, 0);
    __syncthreads();
  }

#pragma unroll
  for (int mf = 0; mf < 4; mf++)
#pragma unroll
    for (int nf = 0; nf < 4; nf++)
#pragma unroll
      for (int i = 0; i < 4; i++) {
        int row = bm + wm * 64 + mf * 16 + l4 * 4 + i;
        int col = bn + wn * 64 + nf * 16 + l15;
        size_t idx = (size_t)row * Ndim + col;
        Cout[idx] = acc[mf][nf][i] + resid[idx];
      }
}

// ---------------------------------------------------------------------------
// Big NT GEMM (logits + v fused): unchanged (at the K=1024 structural
// ceiling, ~848 TF — m248v2).
// ---------------------------------------------------------------------------
__global__ __launch_bounds__(512, 2) void gemm256_nt_kernel(const bf16_t* __restrict__ A,
                                                            const bf16_t* __restrict__ Bw,
                                                            bf16_t* __restrict__ Clg,
                                                            float* __restrict__ Cv) {
  constexpr int K = 1024;
  constexpr int G = K / 64;        // 16 K-tiles
  __shared__ bf16_t As[2 * 16384];   // 64 KB
  __shared__ bf16_t Bs[2 * 16384];   // 64 KB

  const int tid = threadIdx.x;
  const int lane = tid & 63;
  const int w = tid >> 6;
  const int wm = w >> 2;
  const int wn = w & 3;
  const int l15 = lane & 15;
  const int l4 = lane >> 4;

  const int bm = blockIdx.x * 256;
  const int bn = blockIdx.y * 256;

  const bf16_t* Ag = A + (size_t)bm * K;
  const bf16_t* Bg = Bw + (size_t)bn * K;

  int growi[2], gcoli[2];
#pragma unroll
  for (int j = 0; j < 2; ++j) {
    int E = j * 4096 + tid * 8;
    int sub = E >> 9, e = E & 511;
    int rin = e >> 5, cs = e & 31;
    int cin = cs ^ ((rin & 8) ? 16 : 0);
    growi[j] = (sub >> 1) * 16 + rin;
    gcoli[j] = (sub & 1) * 32 + cin;
  }

  const int fbase = l15 * 32 + ((l4 * 8) ^ ((l15 & 8) ? 16 : 0));

  f32x4 acc[8][4];
#pragma unroll
  for (int i = 0; i < 8; i++)
#pragma unroll
    for (int j = 0; j < 4; j++) acc[i][j] = (f32x4){0.f, 0.f, 0.f, 0.f};

  bf16x8 ALo[8], AHi[8], B0r[4], B1r[4];

  auto stageHalf = [&](const bf16_t* Gp, bf16_t* Lp, int bufp, int half, int t2) {
#pragma unroll
    for (int j = 0; j < 2; ++j) {
      const bf16_t* src = Gp + (size_t)(half * 128 + growi[j]) * K + t2 * 64 + gcoli[j];
      __builtin_amdgcn_global_load_lds(
          (const __attribute__((address_space(1))) void*)src,
          (__attribute__((address_space(3))) void*)(Lp + bufp * 16384 + half * 8192 + j * 4096 + w * 512),
          16, 0, 0);
    }
  };

  auto rdA4 = [&](bf16x8* dst, int bufp, int rgrpBase) {
    const bf16_t* base = As + bufp * 16384;
#pragma unroll
    for (int mf = 0; mf < 4; ++mf)
#pragma unroll
      for (int kk = 0; kk < 2; ++kk)
        dst[mf * 2 + kk] = *reinterpret_cast<const bf16x8*>(base + ((rgrpBase + mf) * 2 + kk) * 512 + fbase);
  };
  auto rdA2 = [&](bf16x8* dst, int bufp, int rgrpBase) {
    const bf16_t* base = As + bufp * 16384;
#pragma unroll
    for (int mf = 0; mf < 2; ++mf)
#pragma unroll
      for (int kk = 0; kk < 2; ++kk)
        dst[mf * 2 + kk] = *reinterpret_cast<const bf16x8*>(base + ((rgrpBase + mf) * 2 + kk) * 512 + fbase);
  };
  auto rdB = [&](bf16x8* dst, int bufp, int nfBase) {
    const bf16_t* base = Bs + bufp * 16384;
#pragma unroll
    for (int nf = 0; nf < 2; ++nf)
#pragma unroll
      for (int kk = 0; kk < 2; ++kk)
        dst[nf * 2 + kk] = *reinterpret_cast<const bf16x8*>(base + ((wn * 4 + nfBase + nf) * 2 + kk) * 512 + fbase);
  };
  auto MM = [&](const bf16x8* Af, const bf16x8* Bf, int mfB, int nfB) {
    __builtin_amdgcn_s_setprio(1);
#pragma unroll
    for (int mf = 0; mf < 4; ++mf)
#pragma unroll
      for (int nf = 0; nf < 2; ++nf)
#pragma unroll
        for (int kk = 0; kk < 2; ++kk)
          acc[mfB + mf][nfB + nf] = __builtin_amdgcn_mfma_f32_16x16x32_bf16(
              Af[mf * 2 + kk], Bf[nf * 2 + kk], acc[mfB + mf][nfB + nf], 0, 0, 0);
    __builtin_amdgcn_s_setprio(0);
  };

  // -------- prologue --------
  stageHalf(Bg, Bs, 0, 0, 0);
  stageHalf(Bg, Bs, 0, 1, 0);
  stageHalf(Ag, As, 0, 0, 0);
  stageHalf(Ag, As, 0, 1, 0);
  stageHalf(Ag, As, 1, 0, 1);
  stageHalf(Ag, As, 1, 1, 1);
  asm volatile("s_waitcnt vmcnt(0)" ::: "memory");
  PBAR();
  rdA4(ALo, 0, wm * 8);

#pragma unroll 1
  for (int t = 0; t < G; ++t) {
    const int buf = t & 1;
    const int nbuf = buf ^ 1;

    // ---- P1 ----
    rdB(B0r, buf, 0);
    rdA2(AHi, buf, wm * 8 + 4);
    if (t + 1 < G) stageHalf(Bg, Bs, nbuf, 0, t + 1);
    PBAR();
    MM(ALo, B0r, 0, 0);
    PBAR();

    // ---- P2 ----
    rdB(B1r, buf, 2);
    rdA2(AHi + 4, buf, wm * 8 + 6);
    if (t + 1 < G) stageHalf(Bg, Bs, nbuf, 1, t + 1);
    PBAR();
    MM(ALo, B1r, 0, 2);
    if (t + 1 < G) asm volatile("s_waitcnt vmcnt(4)" ::: "memory");
    PBAR();

    // ---- P3 ----
    if (t + 1 < G) rdA4(ALo, nbuf, wm * 8);
    if (t + 2 < G) stageHalf(Ag, As, buf, 0, t + 2);
    PBAR();
    MM(AHi, B0r, 4, 0);
    PBAR();

    // ---- P4 ----
    if (t + 2 < G) stageHalf(Ag, As, buf, 1, t + 2);
    PBAR();
    MM(AHi, B1r, 4, 2);
    if (t + 2 < G)      asm volatile("s_waitcnt vmcnt(4)" ::: "memory");
    else if (t + 1 < G) asm volatile("s_waitcnt vmcnt(0)" ::: "memory");
    PBAR();
  }

  // -------- epilogue --------
  if (blockIdx.y < 68) {
#pragma unroll
    for (int mf = 0; mf < 8; ++mf)
#pragma unroll
      for (int nf = 0; nf < 4; ++nf)
#pragma unroll
        for (int i = 0; i < 4; ++i) {
          int row = bm + wm * 128 + mf * 16 + l4 * 4 + i;
          int col = bn + wn * 64 + nf * 16 + l15;
          Clg[(size_t)row * NA + col] = (bf16_t)acc[mf][nf][i];
        }
  } else {
    int cb = bn - NA;
#pragma unroll
    for (int mf = 0; mf < 8; ++mf)
#pragma unroll
      for (int nf = 0; nf < 4; ++nf)
#pragma unroll
        for (int i = 0; i < 4; ++i) {
          int row = bm + wm * 128 + mf * 16 + l4 * 4 + i;
          int col = cb + wn * 64 + nf * 16 + l15;
          Cv[(size_t)row * D_DIM + col] = acc[mf][nf][i];
        }
  }
}

// ---------------------------------------------------------------------------
// In-lane softmax over 17 logits in permuted [h][j][i] layout:
// lane i's j-th value sits at base + j*16 (base = lg + r*NA + h*272 + i).
// Each load is 32B-contiguous per 16-lane group -> coalesced.
// ---------------------------------------------------------------------------
__device__ __forceinline__ void softmax17s(const bf16_t* __restrict__ bp, float vval,
                                           f32x4& a0, f32x4& a1, f32x4& a2, f32x4& a3,
                                           float& u) {
  const u16* lp = reinterpret_cast<const u16*>(bp);
  float e[17];
  float mx = -1e30f;
#pragma unroll
  for (int j = 0; j < 17; ++j) {
    e[j] = __uint_as_float(((unsigned)lp[j * 16]) << 16);
    mx = fmaxf(mx, e[j]);
  }
  float s = 0.f;
#pragma unroll
  for (int j = 0; j < 17; ++j) {
    e[j] = __expf(e[j] - mx);
    s += e[j];
  }
  float inv = 1.0f / s;
  a0 = (f32x4){e[1] * inv, e[2] * inv, e[3] * inv, e[4] * inv};
  a1 = (f32x4){e[5] * inv, e[6] * inv, e[7] * inv, e[8] * inv};
  a2 = (f32x4){e[9] * inv, e[10] * inv, e[11] * inv, e[12] * inv};
  a3 = (f32x4){e[13] * inv, e[14] * inv, e[15] * inv, e[16] * inv};
  u = e[0] * inv * vval;
}

// ---------------------------------------------------------------------------
// scanA: per (chain, chunk) chunk summary (P, q)
// ---------------------------------------------------------------------------
__global__ __launch_bounds__(256) void scanA_kernel(const bf16_t* __restrict__ lg,
                                                    const float* __restrict__ v,
                                                    float* __restrict__ sum) {
  int bc = blockIdx.x;
  int b = bc >> 6;
  int c = bc & 63;
  int g = threadIdx.x >> 4;
  int i = threadIdx.x & 15;
  int h = blockIdx.y * 16 + g;
  int chain = b * 64 + h;
  int rbase = b * T_DIM + c * CL;

  __shared__ float Arows[16][16][16];
  __shared__ float Us[16][16];

  f32x4 R0 = (f32x4){i == 0 ? 1.f : 0.f, i == 1 ? 1.f : 0.f, i == 2 ? 1.f : 0.f, i == 3 ? 1.f : 0.f};
  f32x4 R1 = (f32x4){i == 4 ? 1.f : 0.f, i == 5 ? 1.f : 0.f, i == 6 ? 1.f : 0.f, i == 7 ? 1.f : 0.f};
  f32x4 R2 = (f32x4){i == 8 ? 1.f : 0.f, i == 9 ? 1.f : 0.f, i == 10 ? 1.f : 0.f, i == 11 ? 1.f : 0.f};
  f32x4 R3 = (f32x4){i == 12 ? 1.f : 0.f, i == 13 ? 1.f : 0.f, i == 14 ? 1.f : 0.f, i == 15 ? 1.f : 0.f};
  float q = 0.f;

#pragma unroll 1
  for (int tau = CL - 1; tau >= 0; --tau) {
    int r = rbase + tau;
    float vval = v[(size_t)r * D_DIM + h * 16 + i];
    f32x4 a0, a1, a2, a3;
    float uu;
    softmax17s(lg + (size_t)r * NA + h * 272 + i, vval, a0, a1, a2, a3, uu);

    *reinterpret_cast<f32x4*>(&Arows[g][i][0]) = a0;
    *reinterpret_cast<f32x4*>(&Arows[g][i][4]) = a1;
    *reinterpret_cast<f32x4*>(&Arows[g][i][8]) = a2;
    *reinterpret_cast<f32x4*>(&Arows[g][i][12]) = a3;
    Us[g][i] = uu;
    asm volatile("s_waitcnt lgkmcnt(0)" ::: "memory");
    __builtin_amdgcn_sched_barrier(0);

    f32x4 u0 = *reinterpret_cast<const f32x4*>(&Us[g][0]);
    f32x4 u1 = *reinterpret_cast<const f32x4*>(&Us[g][4]);
    f32x4 u2 = *reinterpret_cast<const f32x4*>(&Us[g][8]);
    f32x4 u3 = *reinterpret_cast<const f32x4*>(&Us[g][12]);
    float qa = fmaf(R0[0], u0[0], fmaf(R0[1], u0[1], fmaf(R0[2], u0[2], R0[3] * u0[3])));
    float qb = fmaf(R1[0], u1[0], fmaf(R1[1], u1[1], fmaf(R1[2], u1[2], R1[3] * u1[3])));
    float qc = fmaf(R2[0], u2[0], fmaf(R2[1], u2[1], fmaf(R2[2], u2[2], R2[3] * u2[3])));
    float qd = fmaf(R3[0], u3[0], fmaf(R3[1], u3[1], fmaf(R3[2], u3[2], R3[3] * u3[3])));
    q += (qa + qb) + (qc + qd);

    f32x4 n0 = (f32x4){0.f, 0.f, 0.f, 0.f}, n1 = n0, n2 = n0, n3 = n0;
#pragma unroll
    for (int k = 0; k < 16; ++k) {
      float rk = (k < 4) ? R0[k & 3] : (k < 8) ? R1[k & 3] : (k < 12) ? R2[k & 3] : R3[k & 3];
      f32x4 b0 = *reinterpret_cast<const f32x4*>(&Arows[g][k][0]);
      f32x4 b1 = *reinterpret_cast<const f32x4*>(&Arows[g][k][4]);
      f32x4 b2 = *reinterpret_cast<const f32x4*>(&Arows[g][k][8]);
      f32x4 b3 = *reinterpret_cast<const f32x4*>(&Arows[g][k][12]);
#pragma unroll
      for (int e2 = 0; e2 < 4; ++e2) {
        n0[e2] = fmaf(rk, b0[e2], n0[e2]);
        n1[e2] = fmaf(rk, b1[e2], n1[e2]);
        n2[e2] = fmaf(rk, b2[e2], n2[e2]);
        n3[e2] = fmaf(rk, b3[e2], n3[e2]);
      }
    }
    R0 = n0; R1 = n1; R2 = n2; R3 = n3;
  }

  float* sp = sum + (size_t)(chain * NC + c) * 272;
  *reinterpret_cast<f32x4*>(&sp[i * 16 + 0]) = R0;
  *reinterpret_cast<f32x4*>(&sp[i * 16 + 4]) = R1;
  *reinterpret_cast<f32x4*>(&sp[i * 16 + 8]) = R2;
  *reinterpret_cast<f32x4*>(&sp[i * 16 + 12]) = R3;
  sp[256 + i] = q;
}

// ---------------------------------------------------------------------------
// scanB: serial scan over 64 chunk summaries per chain (unchanged)
// ---------------------------------------------------------------------------
__global__ __launch_bounds__(64) void scanB_kernel(const float* __restrict__ sum,
                                                   float* __restrict__ sinit) {
  int chain = blockIdx.x;
  int lane = threadIdx.x;
  int i = lane & 15;

  __shared__ float seg[2][2176];

  const float* gbase = sum + (size_t)chain * NC * 272;

  auto load_seg = [&](int s, int buf) {
#pragma unroll
    for (int r = 0; r < 9; ++r) {
      int idx = r * 256 + lane * 4;
      if (idx < 2176) {
        __builtin_amdgcn_global_load_lds(
            (const __attribute__((address_space(1))) void*)(gbase + (size_t)s * 2176 + idx),
            (__attribute__((address_space(3))) void*)(&seg[buf][r * 256]), 16, 0, 0);
      }
    }
  };

  load_seg(0, 0);
  VM0();

  f32x4 S0 = (f32x4){0.f, 0.f, 0.f, 0.f}, S1 = S0, S2 = S0, S3 = S0;
  float own = 0.f;

  for (int sg = 0; sg < 8; ++sg) {
    int buf = sg & 1;
    if (sg + 1 < 8) load_seg(sg + 1, buf ^ 1);
#pragma unroll 1
    for (int cc = 0; cc < 8; ++cc) {
      int c = sg * 8 + cc;
      const float* Pb = &seg[buf][cc * 272];
      if (lane < 16) sinit[(size_t)(chain * NC + c) * 16 + i] = own;

      f32x4 p0 = *reinterpret_cast<const f32x4*>(&Pb[i * 16 + 0]);
      f32x4 p1 = *reinterpret_cast<const f32x4*>(&Pb[i * 16 + 4]);
      f32x4 p2 = *reinterpret_cast<const f32x4*>(&Pb[i * 16 + 8]);
      f32x4 p3 = *reinterpret_cast<const f32x4*>(&Pb[i * 16 + 12]);
      float qq = Pb[256 + i];

      float pa = fmaf(p0[0], S0[0], fmaf(p0[1], S0[1], fmaf(p0[2], S0[2], p0[3] * S0[3])));
      float pb = fmaf(p1[0], S1[0], fmaf(p1[1], S1[1], fmaf(p1[2], S1[2], p1[3] * S1[3])));
      float pc = fmaf(p2[0], S2[0], fmaf(p2[1], S2[1], fmaf(p2[2], S2[2], p2[3] * S2[3])));
      float pd = fmaf(p3[0], S3[0], fmaf(p3[1], S3[1], fmaf(p3[2], S3[2], p3[3] * S3[3])));
      float p = (pa + pb) + (pc + pd) + qq;
      own = p;

#pragma unroll
      for (int j = 0; j < 4; ++j) {
        S0[j] = __shfl(p, j, 64);
        S1[j] = __shfl(p, 4 + j, 64);
        S2[j] = __shfl(p, 8 + j, 64);
        S3[j] = __shfl(p, 12 + j, 64);
      }
    }
    if (sg + 1 < 8) VM0();
  }
}

// ---------------------------------------------------------------------------
// scanC: re-run each chunk from its s_init, writing y
// ---------------------------------------------------------------------------
__global__ __launch_bounds__(256) void scanC_kernel(const bf16_t* __restrict__ lg,
                                                    const float* __restrict__ v,
                                                    const float* __restrict__ sinit,
                                                    bf16_t* __restrict__ y) {
  int bc = blockIdx.x;
  int b = bc >> 6;
  int c = bc & 63;
  int g = threadIdx.x >> 4;
  int i = threadIdx.x & 15;
  int h = blockIdx.y * 16 + g;
  int chain = b * 64 + h;
  int rbase = b * T_DIM + c * CL;

  __shared__ float Sb[16][16];

  const float* ip = sinit + (size_t)(chain * NC + c) * 16;
  f32x4 S0 = *reinterpret_cast<const f32x4*>(&ip[0]);
  f32x4 S1 = *reinterpret_cast<const f32x4*>(&ip[4]);
  f32x4 S2 = *reinterpret_cast<const f32x4*>(&ip[8]);
  f32x4 S3 = *reinterpret_cast<const f32x4*>(&ip[12]);

#pragma unroll 1
  for (int t = 0; t < CL; ++t) {
    int r = rbase + t;
    float vval = v[(size_t)r * D_DIM + h * 16 + i];
    f32x4 a0, a1, a2, a3;
    float uu;
    softmax17s(lg + (size_t)r * NA + h * 272 + i, vval, a0, a1, a2, a3, uu);

    float pa = fmaf(a0[0], S0[0], fmaf(a0[1], S0[1], fmaf(a0[2], S0[2], a0[3] * S0[3])));
    float pb = fmaf(a1[0], S1[0], fmaf(a1[1], S1[1], fmaf(a1[2], S1[2], a1[3] * S1[3])));
    float pc = fmaf(a2[0], S2[0], fmaf(a2[1], S2[1], fmaf(a2[2], S2[2], a2[3] * S2[3])));
    float pd = fmaf(a3[0], S3[0], fmaf(a3[1], S3[1], fmaf(a3[2], S3[2], a3[3] * S3[3])));
    float p = (pa + pb) + (pc + pd) + uu;

    y[(size_t)r * D_DIM + h * 16 + i] = (bf16_t)p;

    Sb[g][i] = p;
    asm volatile("s_waitcnt lgkmcnt(0)" ::: "memory");
    __builtin_amdgcn_sched_barrier(0);
    S0 = *reinterpret_cast<const f32x4*>(&Sb[g][0]);
    S1 = *reinterpret_cast<const f32x4*>(&Sb[g][4]);
    S2 = *reinterpret_cast<const f32x4*>(&Sb[g][8]);
    S3 = *reinterpret_cast<const f32x4*>(&Sb[g][12]);
  }
}

// ---------------------------------------------------------------------------
extern "C" void kernel_launch(void* const* d_in, const int* in_sizes, int n_in,
                              void* d_out, int out_size, void* d_ws, size_t ws_size,
                              hipStream_t stream) {
  const float* x      = (const float*)d_in[0];
  const float* norm_w = (const float*)d_in[1];
  const float* W_v    = (const float*)d_in[2];
  const float* W_a    = (const float*)d_in[3];
  const float* W_out  = (const float*)d_in[4];

  char* ws = (char*)d_ws;
  size_t off = 0;
  auto alloc = [&](size_t bytes) {
    void* p = ws + off;
    off += (bytes + 255) & ~(size_t)255;
    return p;
  };
  bf16_t* wcat = (bf16_t*)alloc((size_t)NCAT * D_DIM * 2);         // 37.75 MB
  bf16_t* wo_b = (bf16_t*)alloc((size_t)D_DIM * D_DIM * 2);        // 2 MB
  bf16_t* h_b  = (bf16_t*)alloc((size_t)NT * D_DIM * 2);           // 8 MB
  float*  v_f  = (float*)alloc((size_t)NT * D_DIM * 4);            // 16 MB
  bf16_t* lg_b = (bf16_t*)alloc((size_t)NT * NA * 2);              // 142.6 MB
  bf16_t* y_b  = (bf16_t*)alloc((size_t)NT * D_DIM * 2);           // 8 MB
  float*  sum_f   = (float*)alloc((size_t)256 * NC * 272 * 4);     // 17.8 MB
  float*  sinit_f = (float*)alloc((size_t)256 * NC * 16 * 4);      // 1.05 MB

  prep_kernel<<<NT + 2048, 256, 0, stream>>>(x, norm_w, W_a, W_v, W_out,
                                             h_b, wcat, wo_b);

  gemm256_nt_kernel<<<dim3(NT / 256, NCAT / 256), 512, 0, stream>>>(h_b, wcat, lg_b, v_f);

  scanA_kernel<<<dim3(256, 4), 256, 0, stream>>>(lg_b, v_f, sum_f);
  scanB_kernel<<<256, 64, 0, stream>>>(sum_f, sinit_f);
  scanC_kernel<<<dim3(256, 4), 256, 0, stream>>>(lg_b, v_f, sinit_f, y_b);

  gemm_out_kernel<<<dim3(NT / 128, D_DIM / 128), 256, 0, stream>>>(
      y_b, wo_b, (float*)d_out, x, D_DIM, D_DIM);
}

// Round 11
// 327.119 us; speedup vs baseline: 1.1387x; 1.0311x over previous
//
#include <hip/hip_runtime.h>
#include <hip/hip_bf16.h>
#include <math.h>

// Problem constants
#define B_DIM 4
#define T_DIM 1024
#define D_DIM 1024
#define M_DIM 16
#define H_DIM 64
#define NT    4096            // B*T
#define NA    17408           // H*M*(M+1)
#define NCAT  18432           // NA + D (v-GEMM fused)
#define EPSV  1e-5f
#define CL    16              // scan chunk length
#define NC    64              // chunks per chain (T/CL)

typedef __bf16 bf16_t;
typedef __bf16 bf16x4 __attribute__((ext_vector_type(4)));
typedef __bf16 bf16x8 __attribute__((ext_vector_type(8)));
typedef float  f32x4  __attribute__((ext_vector_type(4)));
typedef unsigned short u16;

#define PBAR() do { asm volatile("" ::: "memory"); __builtin_amdgcn_s_barrier(); asm volatile("" ::: "memory"); } while (0)
#define VM0()   do { asm volatile("s_waitcnt vmcnt(0)" ::: "memory"); __builtin_amdgcn_sched_barrier(0); } while (0)

// ---------------------------------------------------------------------------
// prep kernel: rmsnorm (blocks [0,4096)) + weight cvt (blocks >= 4096).
// W_a rows PERMUTED so logits GEMM emits gates in [h][j][i] order:
//   src row n = h*272 + i*17 + j  ->  dst row n' = h*272 + j*16 + i
// ---------------------------------------------------------------------------
__global__ __launch_bounds__(256) void prep_kernel(const float* __restrict__ x,
                                                   const float* __restrict__ nw,
                                                   const float* __restrict__ Wa,
                                                   const float* __restrict__ Wv,
                                                   const float* __restrict__ Wo,
                                                   bf16_t* __restrict__ h,
                                                   bf16_t* __restrict__ wcat,
                                                   bf16_t* __restrict__ wo) {
  int tid = threadIdx.x;
  if (blockIdx.x < NT) {
    int row = blockIdx.x;
    const float4* xr = reinterpret_cast<const float4*>(x + (size_t)row * D_DIM);
    float4 xv = xr[tid];
    float ss = xv.x * xv.x + xv.y * xv.y + xv.z * xv.z + xv.w * xv.w;
#pragma unroll
    for (int m = 1; m < 64; m <<= 1) ss += __shfl_xor(ss, m, 64);
    __shared__ float red[4];
    int lane = tid & 63, wid = tid >> 6;
    if (lane == 0) red[wid] = ss;
    __syncthreads();
    float tot = red[0] + red[1] + red[2] + red[3];
    float scale = rsqrtf(tot * (1.0f / D_DIM) + EPSV);
    float4 wv = reinterpret_cast<const float4*>(nw)[tid];
    bf16x4 o;
    o[0] = (bf16_t)(xv.x * scale * wv.x);
    o[1] = (bf16_t)(xv.y * scale * wv.y);
    o[2] = (bf16_t)(xv.z * scale * wv.z);
    o[3] = (bf16_t)(xv.w * scale * wv.w);
    reinterpret_cast<bf16x4*>(h)[(size_t)row * 256 + tid] = o;
  } else {
    constexpr int NA4 = NA * D_DIM / 4;
    constexpr int NV4 = D_DIM * D_DIM / 4;
    constexpr int total = NA4 + 2 * NV4;
    int nb = gridDim.x - NT;
    int idx = (blockIdx.x - NT) * 256 + tid;
    int stride = nb * 256;
    for (; idx < total; idx += stride) {
      const float* src; bf16_t* dst; int js, jd;
      if (idx < NA4) {
        src = Wa; dst = wcat; js = idx;
        int row = idx >> 8;
        int c4 = idx & 255;
        int hh = row / 272, r = row - hh * 272;
        int ii = r / 17, jj = r - ii * 17;
        int nrow = hh * 272 + jj * 16 + ii;
        jd = (nrow << 8) + c4;
      } else if (idx < NA4 + NV4) {
        src = Wv; dst = wcat + (size_t)NA * D_DIM; js = idx - NA4; jd = js;
      } else {
        src = Wo; dst = wo; js = idx - NA4 - NV4; jd = js;
      }
      float4 v = reinterpret_cast<const float4*>(src)[js];
      bf16x4 o;
      o[0] = (bf16_t)v.x; o[1] = (bf16_t)v.y; o[2] = (bf16_t)v.z; o[3] = (bf16_t)v.w;
      reinterpret_cast<bf16x4*>(dst)[jd] = o;
    }
  }
}

// ---------------------------------------------------------------------------
// Small NT GEMM: 128x128 tile, BK=32 — final projection with residual add.
// ---------------------------------------------------------------------------
__global__ __launch_bounds__(256) void gemm_out_kernel(const bf16_t* __restrict__ A,
                                                       const bf16_t* __restrict__ Bw,
                                                       float* __restrict__ Cout,
                                                       const float* __restrict__ resid,
                                                       int Ndim, int K) {
  constexpr int BM = 128, BN = 128, BK = 32;
  __shared__ bf16_t As[BM * BK];
  __shared__ bf16_t Bs[BN * BK];

  int tid = threadIdx.x;
  int lane = tid & 63;
  int wid = tid >> 6;
  int wm = wid >> 1, wn = wid & 1;
  int bm = blockIdx.x * BM;
  int bn = blockIdx.y * BN;
  int l15 = lane & 15;
  int l4 = lane >> 4;

  f32x4 acc[4][4];
#pragma unroll
  for (int i = 0; i < 4; i++)
#pragma unroll
    for (int j = 0; j < 4; j++) acc[i][j] = (f32x4){0.f, 0.f, 0.f, 0.f};

  const bf16_t* Ag = A + (size_t)bm * K;
  const bf16_t* Bg = Bw + (size_t)bn * K;
  int srow_lane = lane >> 2;
  int scol = (lane & 3) * 8;

  for (int k0 = 0; k0 < K; k0 += BK) {
#pragma unroll
    for (int i = 0; i < 2; i++) {
      int rbase = wid * 32 + i * 16;
      int r = rbase + srow_lane;
      __builtin_amdgcn_global_load_lds(
          (const __attribute__((address_space(1))) void*)(Ag + (size_t)r * K + k0 + scol),
          (__attribute__((address_space(3))) void*)(As + rbase * BK), 16, 0, 0);
      __builtin_amdgcn_global_load_lds(
          (const __attribute__((address_space(1))) void*)(Bg + (size_t)r * K + k0 + scol),
          (__attribute__((address_space(3))) void*)(Bs + rbase * BK), 16, 0, 0);
    }
    __syncthreads();

    const bf16x8* Asv = reinterpret_cast<const bf16x8*>(As);
    const bf16x8* Bsv = reinterpret_cast<const bf16x8*>(Bs);
    bf16x8 af[4], bfr[4];
#pragma unroll
    for (int mf = 0; mf < 4; mf++)
      af[mf] = Asv[(wm * 64 + mf * 16 + l15) * 4 + l4];
#pragma unroll
    for (int nf = 0; nf < 4; nf++)
      bfr[nf] = Bsv[(wn * 64 + nf * 16 + l15) * 4 + l4];
#pragma unroll
    for (int mf = 0; mf < 4; mf++)
#pragma unroll
      for (int nf = 0; nf < 4; nf++)
        acc[mf][nf] = __builtin_amdgcn_mfma_f32_16x16x32_bf16(af[mf], bfr[nf], acc[mf][nf], 0, 0, 0);
    __syncthreads();
  }

#pragma unroll
  for (int mf = 0; mf < 4; mf++)
#pragma unroll
    for (int nf = 0; nf < 4; nf++)
#pragma unroll
      for (int i = 0; i < 4; i++) {
        int row = bm + wm * 64 + mf * 16 + l4 * 4 + i;
        int col = bn + wn * 64 + nf * 16 + l15;
        size_t idx = (size_t)row * Ndim + col;
        Cout[idx] = acc[mf][nf][i] + resid[idx];
      }
}

// ---------------------------------------------------------------------------
// Big NT GEMM (logits + v fused): 256x256, BK=64, 8 waves, deep pipeline.
// R11 change: pre-MFMA barriers removed (4 barriers/K-tile instead of 8).
// WAR safety: each wave's ds_reads are consumed by its MFMA (compiler lgkm)
// before it crosses the phase-closing barrier; all stage->read pairs keep
// >=2-barrier separation with the same counted vmcnt(4) waits as R7-R10.
// v region written bf16.
// ---------------------------------------------------------------------------
__global__ __launch_bounds__(512, 2) void gemm256_nt_kernel(const bf16_t* __restrict__ A,
                                                            const bf16_t* __restrict__ Bw,
                                                            bf16_t* __restrict__ Clg,
                                                            bf16_t* __restrict__ Cv) {
  constexpr int K = 1024;
  constexpr int G = K / 64;        // 16 K-tiles
  __shared__ bf16_t As[2 * 16384];   // 64 KB
  __shared__ bf16_t Bs[2 * 16384];   // 64 KB

  const int tid = threadIdx.x;
  const int lane = tid & 63;
  const int w = tid >> 6;
  const int wm = w >> 2;
  const int wn = w & 3;
  const int l15 = lane & 15;
  const int l4 = lane >> 4;

  const int bm = blockIdx.x * 256;
  const int bn = blockIdx.y * 256;

  const bf16_t* Ag = A + (size_t)bm * K;
  const bf16_t* Bg = Bw + (size_t)bn * K;

  int growi[2], gcoli[2];
#pragma unroll
  for (int j = 0; j < 2; ++j) {
    int E = j * 4096 + tid * 8;
    int sub = E >> 9, e = E & 511;
    int rin = e >> 5, cs = e & 31;
    int cin = cs ^ ((rin & 8) ? 16 : 0);
    growi[j] = (sub >> 1) * 16 + rin;
    gcoli[j] = (sub & 1) * 32 + cin;
  }

  const int fbase = l15 * 32 + ((l4 * 8) ^ ((l15 & 8) ? 16 : 0));

  f32x4 acc[8][4];
#pragma unroll
  for (int i = 0; i < 8; i++)
#pragma unroll
    for (int j = 0; j < 4; j++) acc[i][j] = (f32x4){0.f, 0.f, 0.f, 0.f};

  bf16x8 ALo[8], AHi[8], B0r[4], B1r[4];

  auto stageHalf = [&](const bf16_t* Gp, bf16_t* Lp, int bufp, int half, int t2) {
#pragma unroll
    for (int j = 0; j < 2; ++j) {
      const bf16_t* src = Gp + (size_t)(half * 128 + growi[j]) * K + t2 * 64 + gcoli[j];
      __builtin_amdgcn_global_load_lds(
          (const __attribute__((address_space(1))) void*)src,
          (__attribute__((address_space(3))) void*)(Lp + bufp * 16384 + half * 8192 + j * 4096 + w * 512),
          16, 0, 0);
    }
  };

  auto rdA4 = [&](bf16x8* dst, int bufp, int rgrpBase) {
    const bf16_t* base = As + bufp * 16384;
#pragma unroll
    for (int mf = 0; mf < 4; ++mf)
#pragma unroll
      for (int kk = 0; kk < 2; ++kk)
        dst[mf * 2 + kk] = *reinterpret_cast<const bf16x8*>(base + ((rgrpBase + mf) * 2 + kk) * 512 + fbase);
  };
  auto rdA2 = [&](bf16x8* dst, int bufp, int rgrpBase) {
    const bf16_t* base = As + bufp * 16384;
#pragma unroll
    for (int mf = 0; mf < 2; ++mf)
#pragma unroll
      for (int kk = 0; kk < 2; ++kk)
        dst[mf * 2 + kk] = *reinterpret_cast<const bf16x8*>(base + ((rgrpBase + mf) * 2 + kk) * 512 + fbase);
  };
  auto rdB = [&](bf16x8* dst, int bufp, int nfBase) {
    const bf16_t* base = Bs + bufp * 16384;
#pragma unroll
    for (int nf = 0; nf < 2; ++nf)
#pragma unroll
      for (int kk = 0; kk < 2; ++kk)
        dst[nf * 2 + kk] = *reinterpret_cast<const bf16x8*>(base + ((wn * 4 + nfBase + nf) * 2 + kk) * 512 + fbase);
  };
  auto MM = [&](const bf16x8* Af, const bf16x8* Bf, int mfB, int nfB) {
    __builtin_amdgcn_s_setprio(1);
#pragma unroll
    for (int mf = 0; mf < 4; ++mf)
#pragma unroll
      for (int nf = 0; nf < 2; ++nf)
#pragma unroll
        for (int kk = 0; kk < 2; ++kk)
          acc[mfB + mf][nfB + nf] = __builtin_amdgcn_mfma_f32_16x16x32_bf16(
              Af[mf * 2 + kk], Bf[nf * 2 + kk], acc[mfB + mf][nfB + nf], 0, 0, 0);
    __builtin_amdgcn_s_setprio(0);
  };

  // -------- prologue --------
  stageHalf(Bg, Bs, 0, 0, 0);
  stageHalf(Bg, Bs, 0, 1, 0);
  stageHalf(Ag, As, 0, 0, 0);
  stageHalf(Ag, As, 0, 1, 0);
  stageHalf(Ag, As, 1, 0, 1);
  stageHalf(Ag, As, 1, 1, 1);
  asm volatile("s_waitcnt vmcnt(0)" ::: "memory");
  PBAR();
  rdA4(ALo, 0, wm * 8);

#pragma unroll 1
  for (int t = 0; t < G; ++t) {
    const int buf = t & 1;
    const int nbuf = buf ^ 1;

    // ---- P1: reads + stage + MFMA (no pre-MFMA barrier) ----
    rdB(B0r, buf, 0);
    rdA2(AHi, buf, wm * 8 + 4);
    if (t + 1 < G) stageHalf(Bg, Bs, nbuf, 0, t + 1);
    MM(ALo, B0r, 0, 0);
    PBAR();

    // ---- P2 ----
    rdB(B1r, buf, 2);
    rdA2(AHi + 4, buf, wm * 8 + 6);
    if (t + 1 < G) stageHalf(Bg, Bs, nbuf, 1, t + 1);
    MM(ALo, B1r, 0, 2);
    if (t + 1 < G) asm volatile("s_waitcnt vmcnt(4)" ::: "memory");
    PBAR();

    // ---- P3 ----
    if (t + 1 < G) rdA4(ALo, nbuf, wm * 8);
    if (t + 2 < G) stageHalf(Ag, As, buf, 0, t + 2);
    MM(AHi, B0r, 4, 0);
    PBAR();

    // ---- P4 ----
    if (t + 2 < G) stageHalf(Ag, As, buf, 1, t + 2);
    MM(AHi, B1r, 4, 2);
    if (t + 2 < G)      asm volatile("s_waitcnt vmcnt(4)" ::: "memory");
    else if (t + 1 < G) asm volatile("s_waitcnt vmcnt(0)" ::: "memory");
    PBAR();
  }

  // -------- epilogue --------
  if (blockIdx.y < 68) {
#pragma unroll
    for (int mf = 0; mf < 8; ++mf)
#pragma unroll
      for (int nf = 0; nf < 4; ++nf)
#pragma unroll
        for (int i = 0; i < 4; ++i) {
          int row = bm + wm * 128 + mf * 16 + l4 * 4 + i;
          int col = bn + wn * 64 + nf * 16 + l15;
          Clg[(size_t)row * NA + col] = (bf16_t)acc[mf][nf][i];
        }
  } else {
    int cb = bn - NA;
#pragma unroll
    for (int mf = 0; mf < 8; ++mf)
#pragma unroll
      for (int nf = 0; nf < 4; ++nf)
#pragma unroll
        for (int i = 0; i < 4; ++i) {
          int row = bm + wm * 128 + mf * 16 + l4 * 4 + i;
          int col = cb + wn * 64 + nf * 16 + l15;
          Cv[(size_t)row * D_DIM + col] = (bf16_t)acc[mf][nf][i];
        }
  }
}

// ---------------------------------------------------------------------------
// In-lane softmax over 17 logits in permuted [h][j][i] layout.
// ---------------------------------------------------------------------------
__device__ __forceinline__ void softmax17s(const bf16_t* __restrict__ bp, float vval,
                                           f32x4& a0, f32x4& a1, f32x4& a2, f32x4& a3,
                                           float& u) {
  const u16* lp = reinterpret_cast<const u16*>(bp);
  float e[17];
  float mx = -1e30f;
#pragma unroll
  for (int j = 0; j < 17; ++j) {
    e[j] = __uint_as_float(((unsigned)lp[j * 16]) << 16);
    mx = fmaxf(mx, e[j]);
  }
  float s = 0.f;
#pragma unroll
  for (int j = 0; j < 17; ++j) {
    e[j] = __expf(e[j] - mx);
    s += e[j];
  }
  float inv = 1.0f / s;
  a0 = (f32x4){e[1] * inv, e[2] * inv, e[3] * inv, e[4] * inv};
  a1 = (f32x4){e[5] * inv, e[6] * inv, e[7] * inv, e[8] * inv};
  a2 = (f32x4){e[9] * inv, e[10] * inv, e[11] * inv, e[12] * inv};
  a3 = (f32x4){e[13] * inv, e[14] * inv, e[15] * inv, e[16] * inv};
  u = e[0] * inv * vval;
}

// ---------------------------------------------------------------------------
// scanA: per (chain, chunk) chunk summary (P, q)
// ---------------------------------------------------------------------------
__global__ __launch_bounds__(256) void scanA_kernel(const bf16_t* __restrict__ lg,
                                                    const bf16_t* __restrict__ v,
                                                    float* __restrict__ sum) {
  int bc = blockIdx.x;
  int b = bc >> 6;
  int c = bc & 63;
  int g = threadIdx.x >> 4;
  int i = threadIdx.x & 15;
  int h = blockIdx.y * 16 + g;
  int chain = b * 64 + h;
  int rbase = b * T_DIM + c * CL;

  __shared__ float Arows[16][16][16];
  __shared__ float Us[16][16];

  f32x4 R0 = (f32x4){i == 0 ? 1.f : 0.f, i == 1 ? 1.f : 0.f, i == 2 ? 1.f : 0.f, i == 3 ? 1.f : 0.f};
  f32x4 R1 = (f32x4){i == 4 ? 1.f : 0.f, i == 5 ? 1.f : 0.f, i == 6 ? 1.f : 0.f, i == 7 ? 1.f : 0.f};
  f32x4 R2 = (f32x4){i == 8 ? 1.f : 0.f, i == 9 ? 1.f : 0.f, i == 10 ? 1.f : 0.f, i == 11 ? 1.f : 0.f};
  f32x4 R3 = (f32x4){i == 12 ? 1.f : 0.f, i == 13 ? 1.f : 0.f, i == 14 ? 1.f : 0.f, i == 15 ? 1.f : 0.f};
  float q = 0.f;

#pragma unroll 1
  for (int tau = CL - 1; tau >= 0; --tau) {
    int r = rbase + tau;
    float vval = (float)v[(size_t)r * D_DIM + h * 16 + i];
    f32x4 a0, a1, a2, a3;
    float uu;
    softmax17s(lg + (size_t)r * NA + h * 272 + i, vval, a0, a1, a2, a3, uu);

    *reinterpret_cast<f32x4*>(&Arows[g][i][0]) = a0;
    *reinterpret_cast<f32x4*>(&Arows[g][i][4]) = a1;
    *reinterpret_cast<f32x4*>(&Arows[g][i][8]) = a2;
    *reinterpret_cast<f32x4*>(&Arows[g][i][12]) = a3;
    Us[g][i] = uu;
    asm volatile("s_waitcnt lgkmcnt(0)" ::: "memory");
    __builtin_amdgcn_sched_barrier(0);

    f32x4 u0 = *reinterpret_cast<const f32x4*>(&Us[g][0]);
    f32x4 u1 = *reinterpret_cast<const f32x4*>(&Us[g][4]);
    f32x4 u2 = *reinterpret_cast<const f32x4*>(&Us[g][8]);
    f32x4 u3 = *reinterpret_cast<const f32x4*>(&Us[g][12]);
    float qa = fmaf(R0[0], u0[0], fmaf(R0[1], u0[1], fmaf(R0[2], u0[2], R0[3] * u0[3])));
    float qb = fmaf(R1[0], u1[0], fmaf(R1[1], u1[1], fmaf(R1[2], u1[2], R1[3] * u1[3])));
    float qc = fmaf(R2[0], u2[0], fmaf(R2[1], u2[1], fmaf(R2[2], u2[2], R2[3] * u2[3])));
    float qd = fmaf(R3[0], u3[0], fmaf(R3[1], u3[1], fmaf(R3[2], u3[2], R3[3] * u3[3])));
    q += (qa + qb) + (qc + qd);

    f32x4 n0 = (f32x4){0.f, 0.f, 0.f, 0.f}, n1 = n0, n2 = n0, n3 = n0;
#pragma unroll
    for (int k = 0; k < 16; ++k) {
      float rk = (k < 4) ? R0[k & 3] : (k < 8) ? R1[k & 3] : (k < 12) ? R2[k & 3] : R3[k & 3];
      f32x4 b0 = *reinterpret_cast<const f32x4*>(&Arows[g][k][0]);
      f32x4 b1 = *reinterpret_cast<const f32x4*>(&Arows[g][k][4]);
      f32x4 b2 = *reinterpret_cast<const f32x4*>(&Arows[g][k][8]);
      f32x4 b3 = *reinterpret_cast<const f32x4*>(&Arows[g][k][12]);
#pragma unroll
      for (int e2 = 0; e2 < 4; ++e2) {
        n0[e2] = fmaf(rk, b0[e2], n0[e2]);
        n1[e2] = fmaf(rk, b1[e2], n1[e2]);
        n2[e2] = fmaf(rk, b2[e2], n2[e2]);
        n3[e2] = fmaf(rk, b3[e2], n3[e2]);
      }
    }
    R0 = n0; R1 = n1; R2 = n2; R3 = n3;
  }

  float* sp = sum + (size_t)(chain * NC + c) * 272;
  *reinterpret_cast<f32x4*>(&sp[i * 16 + 0]) = R0;
  *reinterpret_cast<f32x4*>(&sp[i * 16 + 4]) = R1;
  *reinterpret_cast<f32x4*>(&sp[i * 16 + 8]) = R2;
  *reinterpret_cast<f32x4*>(&sp[i * 16 + 12]) = R3;
  sp[256 + i] = q;
}

// ---------------------------------------------------------------------------
// scanB: serial scan over 64 chunk summaries per chain (unchanged)
// ---------------------------------------------------------------------------
__global__ __launch_bounds__(64) void scanB_kernel(const float* __restrict__ sum,
                                                   float* __restrict__ sinit) {
  int chain = blockIdx.x;
  int lane = threadIdx.x;
  int i = lane & 15;

  __shared__ float seg[2][2176];

  const float* gbase = sum + (size_t)chain * NC * 272;

  auto load_seg = [&](int s, int buf) {
#pragma unroll
    for (int r = 0; r < 9; ++r) {
      int idx = r * 256 + lane * 4;
      if (idx < 2176) {
        __builtin_amdgcn_global_load_lds(
            (const __attribute__((address_space(1))) void*)(gbase + (size_t)s * 2176 + idx),
            (__attribute__((address_space(3))) void*)(&seg[buf][r * 256]), 16, 0, 0);
      }
    }
  };

  load_seg(0, 0);
  VM0();

  f32x4 S0 = (f32x4){0.f, 0.f, 0.f, 0.f}, S1 = S0, S2 = S0, S3 = S0;
  float own = 0.f;

  for (int sg = 0; sg < 8; ++sg) {
    int buf = sg & 1;
    if (sg + 1 < 8) load_seg(sg + 1, buf ^ 1);
#pragma unroll 1
    for (int cc = 0; cc < 8; ++cc) {
      int c = sg * 8 + cc;
      const float* Pb = &seg[buf][cc * 272];
      if (lane < 16) sinit[(size_t)(chain * NC + c) * 16 + i] = own;

      f32x4 p0 = *reinterpret_cast<const f32x4*>(&Pb[i * 16 + 0]);
      f32x4 p1 = *reinterpret_cast<const f32x4*>(&Pb[i * 16 + 4]);
      f32x4 p2 = *reinterpret_cast<const f32x4*>(&Pb[i * 16 + 8]);
      f32x4 p3 = *reinterpret_cast<const f32x4*>(&Pb[i * 16 + 12]);
      float qq = Pb[256 + i];

      float pa = fmaf(p0[0], S0[0], fmaf(p0[1], S0[1], fmaf(p0[2], S0[2], p0[3] * S0[3])));
      float pb = fmaf(p1[0], S1[0], fmaf(p1[1], S1[1], fmaf(p1[2], S1[2], p1[3] * S1[3])));
      float pc = fmaf(p2[0], S2[0], fmaf(p2[1], S2[1], fmaf(p2[2], S2[2], p2[3] * S2[3])));
      float pd = fmaf(p3[0], S3[0], fmaf(p3[1], S3[1], fmaf(p3[2], S3[2], p3[3] * S3[3])));
      float p = (pa + pb) + (pc + pd) + qq;
      own = p;

#pragma unroll
      for (int j = 0; j < 4; ++j) {
        S0[j] = __shfl(p, j, 64);
        S1[j] = __shfl(p, 4 + j, 64);
        S2[j] = __shfl(p, 8 + j, 64);
        S3[j] = __shfl(p, 12 + j, 64);
      }
    }
    if (sg + 1 < 8) VM0();
  }
}

// ---------------------------------------------------------------------------
// scanC: re-run each chunk from its s_init, writing y
// ---------------------------------------------------------------------------
__global__ __launch_bounds__(256) void scanC_kernel(const bf16_t* __restrict__ lg,
                                                    const bf16_t* __restrict__ v,
                                                    const float* __restrict__ sinit,
                                                    bf16_t* __restrict__ y) {
  int bc = blockIdx.x;
  int b = bc >> 6;
  int c = bc & 63;
  int g = threadIdx.x >> 4;
  int i = threadIdx.x & 15;
  int h = blockIdx.y * 16 + g;
  int chain = b * 64 + h;
  int rbase = b * T_DIM + c * CL;

  __shared__ float Sb[16][16];

  const float* ip = sinit + (size_t)(chain * NC + c) * 16;
  f32x4 S0 = *reinterpret_cast<const f32x4*>(&ip[0]);
  f32x4 S1 = *reinterpret_cast<const f32x4*>(&ip[4]);
  f32x4 S2 = *reinterpret_cast<const f32x4*>(&ip[8]);
  f32x4 S3 = *reinterpret_cast<const f32x4*>(&ip[12]);

#pragma unroll 1
  for (int t = 0; t < CL; ++t) {
    int r = rbase + t;
    float vval = (float)v[(size_t)r * D_DIM + h * 16 + i];
    f32x4 a0, a1, a2, a3;
    float uu;
    softmax17s(lg + (size_t)r * NA + h * 272 + i, vval, a0, a1, a2, a3, uu);

    float pa = fmaf(a0[0], S0[0], fmaf(a0[1], S0[1], fmaf(a0[2], S0[2], a0[3] * S0[3])));
    float pb = fmaf(a1[0], S1[0], fmaf(a1[1], S1[1], fmaf(a1[2], S1[2], a1[3] * S1[3])));
    float pc = fmaf(a2[0], S2[0], fmaf(a2[1], S2[1], fmaf(a2[2], S2[2], a2[3] * S2[3])));
    float pd = fmaf(a3[0], S3[0], fmaf(a3[1], S3[1], fmaf(a3[2], S3[2], a3[3] * S3[3])));
    float p = (pa + pb) + (pc + pd) + uu;

    y[(size_t)r * D_DIM + h * 16 + i] = (bf16_t)p;

    Sb[g][i] = p;
    asm volatile("s_waitcnt lgkmcnt(0)" ::: "memory");
    __builtin_amdgcn_sched_barrier(0);
    S0 = *reinterpret_cast<const f32x4*>(&Sb[g][0]);
    S1 = *reinterpret_cast<const f32x4*>(&Sb[g][4]);
    S2 = *reinterpret_cast<const f32x4*>(&Sb[g][8]);
    S3 = *reinterpret_cast<const f32x4*>(&Sb[g][12]);
  }
}

// ---------------------------------------------------------------------------
extern "C" void kernel_launch(void* const* d_in, const int* in_sizes, int n_in,
                              void* d_out, int out_size, void* d_ws, size_t ws_size,
                              hipStream_t stream) {
  const float* x      = (const float*)d_in[0];
  const float* norm_w = (const float*)d_in[1];
  const float* W_v    = (const float*)d_in[2];
  const float* W_a    = (const float*)d_in[3];
  const float* W_out  = (const float*)d_in[4];

  char* ws = (char*)d_ws;
  size_t off = 0;
  auto alloc = [&](size_t bytes) {
    void* p = ws + off;
    off += (bytes + 255) & ~(size_t)255;
    return p;
  };
  bf16_t* wcat = (bf16_t*)alloc((size_t)NCAT * D_DIM * 2);         // 37.75 MB
  bf16_t* wo_b = (bf16_t*)alloc((size_t)D_DIM * D_DIM * 2);        // 2 MB
  bf16_t* h_b  = (bf16_t*)alloc((size_t)NT * D_DIM * 2);           // 8 MB
  bf16_t* v_b  = (bf16_t*)alloc((size_t)NT * D_DIM * 2);           // 8 MB
  bf16_t* lg_b = (bf16_t*)alloc((size_t)NT * NA * 2);              // 142.6 MB
  bf16_t* y_b  = (bf16_t*)alloc((size_t)NT * D_DIM * 2);           // 8 MB
  float*  sum_f   = (float*)alloc((size_t)256 * NC * 272 * 4);     // 17.8 MB
  float*  sinit_f = (float*)alloc((size_t)256 * NC * 16 * 4);      // 1.05 MB

  prep_kernel<<<NT + 2048, 256, 0, stream>>>(x, norm_w, W_a, W_v, W_out,
                                             h_b, wcat, wo_b);

  gemm256_nt_kernel<<<dim3(NT / 256, NCAT / 256), 512, 0, stream>>>(h_b, wcat, lg_b, v_b);

  scanA_kernel<<<dim3(256, 4), 256, 0, stream>>>(lg_b, v_b, sum_f);
  scanB_kernel<<<256, 64, 0, stream>>>(sum_f, sinit_f);
  scanC_kernel<<<dim3(256, 4), 256, 0, stream>>>(lg_b, v_b, sinit_f, y_b);

  gemm_out_kernel<<<dim3(NT / 128, D_DIM / 128), 256, 0, stream>>>(
      y_b, wo_b, (float*)d_out, x, D_DIM, D_DIM);
}

// Round 12
// 311.609 us; speedup vs baseline: 1.1954x; 1.0498x over previous
//
#include <hip/hip_runtime.h>
#include <hip/hip_bf16.h>
#include <math.h>

// Problem constants
#define B_DIM 4
#define T_DIM 1024
#define D_DIM 1024
#define M_DIM 16
#define H_DIM 64
#define NT    4096            // B*T
#define NA    17408           // H*M*(M+1)
#define NCAT  18432           // NA + D (v-GEMM fused)
#define EPSV  1e-5f
#define CL    16              // scan chunk length
#define NC    64              // chunks per chain (T/CL)

typedef __bf16 bf16_t;
typedef __bf16 bf16x4 __attribute__((ext_vector_type(4)));
typedef __bf16 bf16x8 __attribute__((ext_vector_type(8)));
typedef float  f32x4  __attribute__((ext_vector_type(4)));
typedef unsigned short u16;

#define PBAR() do { asm volatile("" ::: "memory"); __builtin_amdgcn_s_barrier(); asm volatile("" ::: "memory"); } while (0)
#define VM0()   do { asm volatile("s_waitcnt vmcnt(0)" ::: "memory"); __builtin_amdgcn_sched_barrier(0); } while (0)

// ---------------------------------------------------------------------------
// prep kernel: rmsnorm (blocks [0,4096)) + weight cvt (blocks >= 4096).
// W_a rows PERMUTED so logits GEMM emits gates in [h][j][i] order.
// ---------------------------------------------------------------------------
__global__ __launch_bounds__(256) void prep_kernel(const float* __restrict__ x,
                                                   const float* __restrict__ nw,
                                                   const float* __restrict__ Wa,
                                                   const float* __restrict__ Wv,
                                                   const float* __restrict__ Wo,
                                                   bf16_t* __restrict__ h,
                                                   bf16_t* __restrict__ wcat,
                                                   bf16_t* __restrict__ wo) {
  int tid = threadIdx.x;
  if (blockIdx.x < NT) {
    int row = blockIdx.x;
    const float4* xr = reinterpret_cast<const float4*>(x + (size_t)row * D_DIM);
    float4 xv = xr[tid];
    float ss = xv.x * xv.x + xv.y * xv.y + xv.z * xv.z + xv.w * xv.w;
#pragma unroll
    for (int m = 1; m < 64; m <<= 1) ss += __shfl_xor(ss, m, 64);
    __shared__ float red[4];
    int lane = tid & 63, wid = tid >> 6;
    if (lane == 0) red[wid] = ss;
    __syncthreads();
    float tot = red[0] + red[1] + red[2] + red[3];
    float scale = rsqrtf(tot * (1.0f / D_DIM) + EPSV);
    float4 wv = reinterpret_cast<const float4*>(nw)[tid];
    bf16x4 o;
    o[0] = (bf16_t)(xv.x * scale * wv.x);
    o[1] = (bf16_t)(xv.y * scale * wv.y);
    o[2] = (bf16_t)(xv.z * scale * wv.z);
    o[3] = (bf16_t)(xv.w * scale * wv.w);
    reinterpret_cast<bf16x4*>(h)[(size_t)row * 256 + tid] = o;
  } else {
    constexpr int NA4 = NA * D_DIM / 4;
    constexpr int NV4 = D_DIM * D_DIM / 4;
    constexpr int total = NA4 + 2 * NV4;
    int nb = gridDim.x - NT;
    int idx = (blockIdx.x - NT) * 256 + tid;
    int stride = nb * 256;
    for (; idx < total; idx += stride) {
      const float* src; bf16_t* dst; int js, jd;
      if (idx < NA4) {
        src = Wa; dst = wcat; js = idx;
        int row = idx >> 8;
        int c4 = idx & 255;
        int hh = row / 272, r = row - hh * 272;
        int ii = r / 17, jj = r - ii * 17;
        int nrow = hh * 272 + jj * 16 + ii;
        jd = (nrow << 8) + c4;
      } else if (idx < NA4 + NV4) {
        src = Wv; dst = wcat + (size_t)NA * D_DIM; js = idx - NA4; jd = js;
      } else {
        src = Wo; dst = wo; js = idx - NA4 - NV4; jd = js;
      }
      float4 v = reinterpret_cast<const float4*>(src)[js];
      bf16x4 o;
      o[0] = (bf16_t)v.x; o[1] = (bf16_t)v.y; o[2] = (bf16_t)v.z; o[3] = (bf16_t)v.w;
      reinterpret_cast<bf16x4*>(dst)[jd] = o;
    }
  }
}

// ---------------------------------------------------------------------------
// Small NT GEMM: 128x128 tile, BK=32 — final projection with residual add.
// ---------------------------------------------------------------------------
__global__ __launch_bounds__(256) void gemm_out_kernel(const bf16_t* __restrict__ A,
                                                       const bf16_t* __restrict__ Bw,
                                                       float* __restrict__ Cout,
                                                       const float* __restrict__ resid,
                                                       int Ndim, int K) {
  constexpr int BM = 128, BN = 128, BK = 32;
  __shared__ bf16_t As[BM * BK];
  __shared__ bf16_t Bs[BN * BK];

  int tid = threadIdx.x;
  int lane = tid & 63;
  int wid = tid >> 6;
  int wm = wid >> 1, wn = wid & 1;
  int bm = blockIdx.x * BM;
  int bn = blockIdx.y * BN;
  int l15 = lane & 15;
  int l4 = lane >> 4;

  f32x4 acc[4][4];
#pragma unroll
  for (int i = 0; i < 4; i++)
#pragma unroll
    for (int j = 0; j < 4; j++) acc[i][j] = (f32x4){0.f, 0.f, 0.f, 0.f};

  const bf16_t* Ag = A + (size_t)bm * K;
  const bf16_t* Bg = Bw + (size_t)bn * K;
  int srow_lane = lane >> 2;
  int scol = (lane & 3) * 8;

  for (int k0 = 0; k0 < K; k0 += BK) {
#pragma unroll
    for (int i = 0; i < 2; i++) {
      int rbase = wid * 32 + i * 16;
      int r = rbase + srow_lane;
      __builtin_amdgcn_global_load_lds(
          (const __attribute__((address_space(1))) void*)(Ag + (size_t)r * K + k0 + scol),
          (__attribute__((address_space(3))) void*)(As + rbase * BK), 16, 0, 0);
      __builtin_amdgcn_global_load_lds(
          (const __attribute__((address_space(1))) void*)(Bg + (size_t)r * K + k0 + scol),
          (__attribute__((address_space(3))) void*)(Bs + rbase * BK), 16, 0, 0);
    }
    __syncthreads();

    const bf16x8* Asv = reinterpret_cast<const bf16x8*>(As);
    const bf16x8* Bsv = reinterpret_cast<const bf16x8*>(Bs);
    bf16x8 af[4], bfr[4];
#pragma unroll
    for (int mf = 0; mf < 4; mf++)
      af[mf] = Asv[(wm * 64 + mf * 16 + l15) * 4 + l4];
#pragma unroll
    for (int nf = 0; nf < 4; nf++)
      bfr[nf] = Bsv[(wn * 64 + nf * 16 + l15) * 4 + l4];
#pragma unroll
    for (int mf = 0; mf < 4; mf++)
#pragma unroll
      for (int nf = 0; nf < 4; nf++)
        acc[mf][nf] = __builtin_amdgcn_mfma_f32_16x16x32_bf16(af[mf], bfr[nf], acc[mf][nf], 0, 0, 0);
    __syncthreads();
  }

#pragma unroll
  for (int mf = 0; mf < 4; mf++)
#pragma unroll
    for (int nf = 0; nf < 4; nf++)
#pragma unroll
      for (int i = 0; i < 4; i++) {
        int row = bm + wm * 64 + mf * 16 + l4 * 4 + i;
        int col = bn + wn * 64 + nf * 16 + l15;
        size_t idx = (size_t)row * Ndim + col;
        Cout[idx] = acc[mf][nf][i] + resid[idx];
      }
}

// ---------------------------------------------------------------------------
// Big NT GEMM (logits + v fused): 256x256, BK=64, 8 waves.
// R12: 2 barriers per K-tile (P2-end, P4-end only). Hazard ledger:
//  RAW: A(t+1) loads complete at P2-end vmcnt(4)+barrier, read in P3;
//       B(t+1) loads complete at P4-end vmcnt(4)+barrier, read next P1.
//  WAR: every stage targets a region whose last reads are >=1 barrier prior,
//       and those reads' data is in registers (compiler lgkm) before any
//       wave can reach the staging phase.
// ---------------------------------------------------------------------------
__global__ __launch_bounds__(512, 2) void gemm256_nt_kernel(const bf16_t* __restrict__ A,
                                                            const bf16_t* __restrict__ Bw,
                                                            bf16_t* __restrict__ Clg,
                                                            bf16_t* __restrict__ Cv) {
  constexpr int K = 1024;
  constexpr int G = K / 64;        // 16 K-tiles
  __shared__ bf16_t As[2 * 16384];   // 64 KB
  __shared__ bf16_t Bs[2 * 16384];   // 64 KB

  const int tid = threadIdx.x;
  const int lane = tid & 63;
  const int w = tid >> 6;
  const int wm = w >> 2;
  const int wn = w & 3;
  const int l15 = lane & 15;
  const int l4 = lane >> 4;

  const int bm = blockIdx.x * 256;
  const int bn = blockIdx.y * 256;

  const bf16_t* Ag = A + (size_t)bm * K;
  const bf16_t* Bg = Bw + (size_t)bn * K;

  int growi[2], gcoli[2];
#pragma unroll
  for (int j = 0; j < 2; ++j) {
    int E = j * 4096 + tid * 8;
    int sub = E >> 9, e = E & 511;
    int rin = e >> 5, cs = e & 31;
    int cin = cs ^ ((rin & 8) ? 16 : 0);
    growi[j] = (sub >> 1) * 16 + rin;
    gcoli[j] = (sub & 1) * 32 + cin;
  }

  const int fbase = l15 * 32 + ((l4 * 8) ^ ((l15 & 8) ? 16 : 0));

  f32x4 acc[8][4];
#pragma unroll
  for (int i = 0; i < 8; i++)
#pragma unroll
    for (int j = 0; j < 4; j++) acc[i][j] = (f32x4){0.f, 0.f, 0.f, 0.f};

  bf16x8 ALo[8], AHi[8], B0r[4], B1r[4];

  auto stageHalf = [&](const bf16_t* Gp, bf16_t* Lp, int bufp, int half, int t2) {
#pragma unroll
    for (int j = 0; j < 2; ++j) {
      const bf16_t* src = Gp + (size_t)(half * 128 + growi[j]) * K + t2 * 64 + gcoli[j];
      __builtin_amdgcn_global_load_lds(
          (const __attribute__((address_space(1))) void*)src,
          (__attribute__((address_space(3))) void*)(Lp + bufp * 16384 + half * 8192 + j * 4096 + w * 512),
          16, 0, 0);
    }
  };

  auto rdA4 = [&](bf16x8* dst, int bufp, int rgrpBase) {
    const bf16_t* base = As + bufp * 16384;
#pragma unroll
    for (int mf = 0; mf < 4; ++mf)
#pragma unroll
      for (int kk = 0; kk < 2; ++kk)
        dst[mf * 2 + kk] = *reinterpret_cast<const bf16x8*>(base + ((rgrpBase + mf) * 2 + kk) * 512 + fbase);
  };
  auto rdA2 = [&](bf16x8* dst, int bufp, int rgrpBase) {
    const bf16_t* base = As + bufp * 16384;
#pragma unroll
    for (int mf = 0; mf < 2; ++mf)
#pragma unroll
      for (int kk = 0; kk < 2; ++kk)
        dst[mf * 2 + kk] = *reinterpret_cast<const bf16x8*>(base + ((rgrpBase + mf) * 2 + kk) * 512 + fbase);
  };
  auto rdB = [&](bf16x8* dst, int bufp, int nfBase) {
    const bf16_t* base = Bs + bufp * 16384;
#pragma unroll
    for (int nf = 0; nf < 2; ++nf)
#pragma unroll
      for (int kk = 0; kk < 2; ++kk)
        dst[nf * 2 + kk] = *reinterpret_cast<const bf16x8*>(base + ((wn * 4 + nfBase + nf) * 2 + kk) * 512 + fbase);
  };
  auto MM = [&](const bf16x8* Af, const bf16x8* Bf, int mfB, int nfB) {
    __builtin_amdgcn_s_setprio(1);
#pragma unroll
    for (int mf = 0; mf < 4; ++mf)
#pragma unroll
      for (int nf = 0; nf < 2; ++nf)
#pragma unroll
        for (int kk = 0; kk < 2; ++kk)
          acc[mfB + mf][nfB + nf] = __builtin_amdgcn_mfma_f32_16x16x32_bf16(
              Af[mf * 2 + kk], Bf[nf * 2 + kk], acc[mfB + mf][nfB + nf], 0, 0, 0);
    __builtin_amdgcn_s_setprio(0);
  };

  // -------- prologue --------
  stageHalf(Bg, Bs, 0, 0, 0);
  stageHalf(Bg, Bs, 0, 1, 0);
  stageHalf(Ag, As, 0, 0, 0);
  stageHalf(Ag, As, 0, 1, 0);
  stageHalf(Ag, As, 1, 0, 1);
  stageHalf(Ag, As, 1, 1, 1);
  asm volatile("s_waitcnt vmcnt(0)" ::: "memory");
  PBAR();
  rdA4(ALo, 0, wm * 8);

#pragma unroll 1
  for (int t = 0; t < G; ++t) {
    const int buf = t & 1;
    const int nbuf = buf ^ 1;

    // ---- P1 (no barrier after) ----
    rdB(B0r, buf, 0);
    rdA2(AHi, buf, wm * 8 + 4);
    if (t + 1 < G) stageHalf(Bg, Bs, nbuf, 0, t + 1);
    MM(ALo, B0r, 0, 0);

    // ---- P2 ----
    rdB(B1r, buf, 2);
    rdA2(AHi + 4, buf, wm * 8 + 6);
    if (t + 1 < G) stageHalf(Bg, Bs, nbuf, 1, t + 1);
    MM(ALo, B1r, 0, 2);
    if (t + 1 < G) asm volatile("s_waitcnt vmcnt(4)" ::: "memory");
    PBAR();

    // ---- P3 (no barrier after) ----
    if (t + 1 < G) rdA4(ALo, nbuf, wm * 8);
    if (t + 2 < G) stageHalf(Ag, As, buf, 0, t + 2);
    MM(AHi, B0r, 4, 0);

    // ---- P4 ----
    if (t + 2 < G) stageHalf(Ag, As, buf, 1, t + 2);
    MM(AHi, B1r, 4, 2);
    if (t + 2 < G)      asm volatile("s_waitcnt vmcnt(4)" ::: "memory");
    else if (t + 1 < G) asm volatile("s_waitcnt vmcnt(0)" ::: "memory");
    PBAR();
  }

  // -------- epilogue --------
  if (blockIdx.y < 68) {
#pragma unroll
    for (int mf = 0; mf < 8; ++mf)
#pragma unroll
      for (int nf = 0; nf < 4; ++nf)
#pragma unroll
        for (int i = 0; i < 4; ++i) {
          int row = bm + wm * 128 + mf * 16 + l4 * 4 + i;
          int col = bn + wn * 64 + nf * 16 + l15;
          Clg[(size_t)row * NA + col] = (bf16_t)acc[mf][nf][i];
        }
  } else {
    int cb = bn - NA;
#pragma unroll
    for (int mf = 0; mf < 8; ++mf)
#pragma unroll
      for (int nf = 0; nf < 4; ++nf)
#pragma unroll
        for (int i = 0; i < 4; ++i) {
          int row = bm + wm * 128 + mf * 16 + l4 * 4 + i;
          int col = cb + wn * 64 + nf * 16 + l15;
          Cv[(size_t)row * D_DIM + col] = (bf16_t)acc[mf][nf][i];
        }
  }
}

// ---------------------------------------------------------------------------
// In-lane softmax over 17 logits in permuted [h][j][i] layout.
// ---------------------------------------------------------------------------
__device__ __forceinline__ void softmax17s(const bf16_t* __restrict__ bp, float vval,
                                           f32x4& a0, f32x4& a1, f32x4& a2, f32x4& a3,
                                           float& u) {
  const u16* lp = reinterpret_cast<const u16*>(bp);
  float e[17];
  float mx = -1e30f;
#pragma unroll
  for (int j = 0; j < 17; ++j) {
    e[j] = __uint_as_float(((unsigned)lp[j * 16]) << 16);
    mx = fmaxf(mx, e[j]);
  }
  float s = 0.f;
#pragma unroll
  for (int j = 0; j < 17; ++j) {
    e[j] = __expf(e[j] - mx);
    s += e[j];
  }
  float inv = 1.0f / s;
  a0 = (f32x4){e[1] * inv, e[2] * inv, e[3] * inv, e[4] * inv};
  a1 = (f32x4){e[5] * inv, e[6] * inv, e[7] * inv, e[8] * inv};
  a2 = (f32x4){e[9] * inv, e[10] * inv, e[11] * inv, e[12] * inv};
  a3 = (f32x4){e[13] * inv, e[14] * inv, e[15] * inv, e[16] * inv};
  u = e[0] * inv * vval;
}

// ---------------------------------------------------------------------------
// scanA: per (chain, chunk) chunk summary (P, q).
// R12: Arows group stride padded to 264 f32 (1056 B) -> the 4 groups'
// broadcast reads at fixed k hit banks {8g+16k}, all distinct: conflict-free
// (was 4-way). Manual lgkm/sched_barrier removed (compiler orders same-array
// LDS write->read and inserts minimal waits).
// ---------------------------------------------------------------------------
#define AGS 264   // Arows group stride in f32

__global__ __launch_bounds__(256) void scanA_kernel(const bf16_t* __restrict__ lg,
                                                    const bf16_t* __restrict__ v,
                                                    float* __restrict__ sum) {
  int bc = blockIdx.x;
  int b = bc >> 6;
  int c = bc & 63;
  int g = threadIdx.x >> 4;
  int i = threadIdx.x & 15;
  int h = blockIdx.y * 16 + g;
  int chain = b * 64 + h;
  int rbase = b * T_DIM + c * CL;

  __shared__ float Arows[16 * AGS];     // padded group stride
  __shared__ float Us[16 * 20];         // group stride 20 f32

  float* Ag_ = Arows + g * AGS;
  float* Ug_ = Us + g * 20;

  f32x4 R0 = (f32x4){i == 0 ? 1.f : 0.f, i == 1 ? 1.f : 0.f, i == 2 ? 1.f : 0.f, i == 3 ? 1.f : 0.f};
  f32x4 R1 = (f32x4){i == 4 ? 1.f : 0.f, i == 5 ? 1.f : 0.f, i == 6 ? 1.f : 0.f, i == 7 ? 1.f : 0.f};
  f32x4 R2 = (f32x4){i == 8 ? 1.f : 0.f, i == 9 ? 1.f : 0.f, i == 10 ? 1.f : 0.f, i == 11 ? 1.f : 0.f};
  f32x4 R3 = (f32x4){i == 12 ? 1.f : 0.f, i == 13 ? 1.f : 0.f, i == 14 ? 1.f : 0.f, i == 15 ? 1.f : 0.f};
  float q = 0.f;

#pragma unroll 1
  for (int tau = CL - 1; tau >= 0; --tau) {
    int r = rbase + tau;
    float vval = (float)v[(size_t)r * D_DIM + h * 16 + i];
    f32x4 a0, a1, a2, a3;
    float uu;
    softmax17s(lg + (size_t)r * NA + h * 272 + i, vval, a0, a1, a2, a3, uu);

    *reinterpret_cast<f32x4*>(&Ag_[i * 16 + 0]) = a0;
    *reinterpret_cast<f32x4*>(&Ag_[i * 16 + 4]) = a1;
    *reinterpret_cast<f32x4*>(&Ag_[i * 16 + 8]) = a2;
    *reinterpret_cast<f32x4*>(&Ag_[i * 16 + 12]) = a3;
    Ug_[i] = uu;

    f32x4 u0 = *reinterpret_cast<const f32x4*>(&Ug_[0]);
    f32x4 u1 = *reinterpret_cast<const f32x4*>(&Ug_[4]);
    f32x4 u2 = *reinterpret_cast<const f32x4*>(&Ug_[8]);
    f32x4 u3 = *reinterpret_cast<const f32x4*>(&Ug_[12]);
    float qa = fmaf(R0[0], u0[0], fmaf(R0[1], u0[1], fmaf(R0[2], u0[2], R0[3] * u0[3])));
    float qb = fmaf(R1[0], u1[0], fmaf(R1[1], u1[1], fmaf(R1[2], u1[2], R1[3] * u1[3])));
    float qc = fmaf(R2[0], u2[0], fmaf(R2[1], u2[1], fmaf(R2[2], u2[2], R2[3] * u2[3])));
    float qd = fmaf(R3[0], u3[0], fmaf(R3[1], u3[1], fmaf(R3[2], u3[2], R3[3] * u3[3])));
    q += (qa + qb) + (qc + qd);

    f32x4 n0 = (f32x4){0.f, 0.f, 0.f, 0.f}, n1 = n0, n2 = n0, n3 = n0;
#pragma unroll
    for (int k = 0; k < 16; ++k) {
      float rk = (k < 4) ? R0[k & 3] : (k < 8) ? R1[k & 3] : (k < 12) ? R2[k & 3] : R3[k & 3];
      f32x4 b0 = *reinterpret_cast<const f32x4*>(&Ag_[k * 16 + 0]);
      f32x4 b1 = *reinterpret_cast<const f32x4*>(&Ag_[k * 16 + 4]);
      f32x4 b2 = *reinterpret_cast<const f32x4*>(&Ag_[k * 16 + 8]);
      f32x4 b3 = *reinterpret_cast<const f32x4*>(&Ag_[k * 16 + 12]);
#pragma unroll
      for (int e2 = 0; e2 < 4; ++e2) {
        n0[e2] = fmaf(rk, b0[e2], n0[e2]);
        n1[e2] = fmaf(rk, b1[e2], n1[e2]);
        n2[e2] = fmaf(rk, b2[e2], n2[e2]);
        n3[e2] = fmaf(rk, b3[e2], n3[e2]);
      }
    }
    R0 = n0; R1 = n1; R2 = n2; R3 = n3;
  }

  float* sp = sum + (size_t)(chain * NC + c) * 272;
  *reinterpret_cast<f32x4*>(&sp[i * 16 + 0]) = R0;
  *reinterpret_cast<f32x4*>(&sp[i * 16 + 4]) = R1;
  *reinterpret_cast<f32x4*>(&sp[i * 16 + 8]) = R2;
  *reinterpret_cast<f32x4*>(&sp[i * 16 + 12]) = R3;
  sp[256 + i] = q;
}

// ---------------------------------------------------------------------------
// scanB: serial scan over 64 chunk summaries per chain (unchanged)
// ---------------------------------------------------------------------------
__global__ __launch_bounds__(64) void scanB_kernel(const float* __restrict__ sum,
                                                   float* __restrict__ sinit) {
  int chain = blockIdx.x;
  int lane = threadIdx.x;
  int i = lane & 15;

  __shared__ float seg[2][2176];

  const float* gbase = sum + (size_t)chain * NC * 272;

  auto load_seg = [&](int s, int buf) {
#pragma unroll
    for (int r = 0; r < 9; ++r) {
      int idx = r * 256 + lane * 4;
      if (idx < 2176) {
        __builtin_amdgcn_global_load_lds(
            (const __attribute__((address_space(1))) void*)(gbase + (size_t)s * 2176 + idx),
            (__attribute__((address_space(3))) void*)(&seg[buf][r * 256]), 16, 0, 0);
      }
    }
  };

  load_seg(0, 0);
  VM0();

  f32x4 S0 = (f32x4){0.f, 0.f, 0.f, 0.f}, S1 = S0, S2 = S0, S3 = S0;
  float own = 0.f;

  for (int sg = 0; sg < 8; ++sg) {
    int buf = sg & 1;
    if (sg + 1 < 8) load_seg(sg + 1, buf ^ 1);
#pragma unroll 1
    for (int cc = 0; cc < 8; ++cc) {
      int c = sg * 8 + cc;
      const float* Pb = &seg[buf][cc * 272];
      if (lane < 16) sinit[(size_t)(chain * NC + c) * 16 + i] = own;

      f32x4 p0 = *reinterpret_cast<const f32x4*>(&Pb[i * 16 + 0]);
      f32x4 p1 = *reinterpret_cast<const f32x4*>(&Pb[i * 16 + 4]);
      f32x4 p2 = *reinterpret_cast<const f32x4*>(&Pb[i * 16 + 8]);
      f32x4 p3 = *reinterpret_cast<const f32x4*>(&Pb[i * 16 + 12]);
      float qq = Pb[256 + i];

      float pa = fmaf(p0[0], S0[0], fmaf(p0[1], S0[1], fmaf(p0[2], S0[2], p0[3] * S0[3])));
      float pb = fmaf(p1[0], S1[0], fmaf(p1[1], S1[1], fmaf(p1[2], S1[2], p1[3] * S1[3])));
      float pc = fmaf(p2[0], S2[0], fmaf(p2[1], S2[1], fmaf(p2[2], S2[2], p2[3] * S2[3])));
      float pd = fmaf(p3[0], S3[0], fmaf(p3[1], S3[1], fmaf(p3[2], S3[2], p3[3] * S3[3])));
      float p = (pa + pb) + (pc + pd) + qq;
      own = p;

#pragma unroll
      for (int j = 0; j < 4; ++j) {
        S0[j] = __shfl(p, j, 64);
        S1[j] = __shfl(p, 4 + j, 64);
        S2[j] = __shfl(p, 8 + j, 64);
        S3[j] = __shfl(p, 12 + j, 64);
      }
    }
    if (sg + 1 < 8) VM0();
  }
}

// ---------------------------------------------------------------------------
// scanC: re-run each chunk from its s_init, writing y.
// Manual lgkm/sched_barrier removed (compiler orders Sb write->read).
// ---------------------------------------------------------------------------
__global__ __launch_bounds__(256) void scanC_kernel(const bf16_t* __restrict__ lg,
                                                    const bf16_t* __restrict__ v,
                                                    const float* __restrict__ sinit,
                                                    bf16_t* __restrict__ y) {
  int bc = blockIdx.x;
  int b = bc >> 6;
  int c = bc & 63;
  int g = threadIdx.x >> 4;
  int i = threadIdx.x & 15;
  int h = blockIdx.y * 16 + g;
  int chain = b * 64 + h;
  int rbase = b * T_DIM + c * CL;

  __shared__ float Sb[16][20];

  const float* ip = sinit + (size_t)(chain * NC + c) * 16;
  f32x4 S0 = *reinterpret_cast<const f32x4*>(&ip[0]);
  f32x4 S1 = *reinterpret_cast<const f32x4*>(&ip[4]);
  f32x4 S2 = *reinterpret_cast<const f32x4*>(&ip[8]);
  f32x4 S3 = *reinterpret_cast<const f32x4*>(&ip[12]);

#pragma unroll 1
  for (int t = 0; t < CL; ++t) {
    int r = rbase + t;
    float vval = (float)v[(size_t)r * D_DIM + h * 16 + i];
    f32x4 a0, a1, a2, a3;
    float uu;
    softmax17s(lg + (size_t)r * NA + h * 272 + i, vval, a0, a1, a2, a3, uu);

    float pa = fmaf(a0[0], S0[0], fmaf(a0[1], S0[1], fmaf(a0[2], S0[2], a0[3] * S0[3])));
    float pb = fmaf(a1[0], S1[0], fmaf(a1[1], S1[1], fmaf(a1[2], S1[2], a1[3] * S1[3])));
    float pc = fmaf(a2[0], S2[0], fmaf(a2[1], S2[1], fmaf(a2[2], S2[2], a2[3] * S2[3])));
    float pd = fmaf(a3[0], S3[0], fmaf(a3[1], S3[1], fmaf(a3[2], S3[2], a3[3] * S3[3])));
    float p = (pa + pb) + (pc + pd) + uu;

    y[(size_t)r * D_DIM + h * 16 + i] = (bf16_t)p;

    Sb[g][i] = p;
    S0 = *reinterpret_cast<const f32x4*>(&Sb[g][0]);
    S1 = *reinterpret_cast<const f32x4*>(&Sb[g][4]);
    S2 = *reinterpret_cast<const f32x4*>(&Sb[g][8]);
    S3 = *reinterpret_cast<const f32x4*>(&Sb[g][12]);
  }
}

// ---------------------------------------------------------------------------
extern "C" void kernel_launch(void* const* d_in, const int* in_sizes, int n_in,
                              void* d_out, int out_size, void* d_ws, size_t ws_size,
                              hipStream_t stream) {
  const float* x      = (const float*)d_in[0];
  const float* norm_w = (const float*)d_in[1];
  const float* W_v    = (const float*)d_in[2];
  const float* W_a    = (const float*)d_in[3];
  const float* W_out  = (const float*)d_in[4];

  char* ws = (char*)d_ws;
  size_t off = 0;
  auto alloc = [&](size_t bytes) {
    void* p = ws + off;
    off += (bytes + 255) & ~(size_t)255;
    return p;
  };
  bf16_t* wcat = (bf16_t*)alloc((size_t)NCAT * D_DIM * 2);         // 37.75 MB
  bf16_t* wo_b = (bf16_t*)alloc((size_t)D_DIM * D_DIM * 2);        // 2 MB
  bf16_t* h_b  = (bf16_t*)alloc((size_t)NT * D_DIM * 2);           // 8 MB
  bf16_t* v_b  = (bf16_t*)alloc((size_t)NT * D_DIM * 2);           // 8 MB
  bf16_t* lg_b = (bf16_t*)alloc((size_t)NT * NA * 2);              // 142.6 MB
  bf16_t* y_b  = (bf16_t*)alloc((size_t)NT * D_DIM * 2);           // 8 MB
  float*  sum_f   = (float*)alloc((size_t)256 * NC * 272 * 4);     // 17.8 MB
  float*  sinit_f = (float*)alloc((size_t)256 * NC * 16 * 4);      // 1.05 MB

  prep_kernel<<<NT + 2048, 256, 0, stream>>>(x, norm_w, W_a, W_v, W_out,
                                             h_b, wcat, wo_b);

  gemm256_nt_kernel<<<dim3(NT / 256, NCAT / 256), 512, 0, stream>>>(h_b, wcat, lg_b, v_b);

  scanA_kernel<<<dim3(256, 4), 256, 0, stream>>>(lg_b, v_b, sum_f);
  scanB_kernel<<<256, 64, 0, stream>>>(sum_f, sinit_f);
  scanC_kernel<<<dim3(256, 4), 256, 0, stream>>>(lg_b, v_b, sinit_f, y_b);

  gemm_out_kernel<<<dim3(NT / 128, D_DIM / 128), 256, 0, stream>>>(
      y_b, wo_b, (float*)d_out, x, D_DIM, D_DIM);
}